// Round 1
// baseline (815.792 us; speedup 1.0000x reference)
//
#include <hip/hip_runtime.h>

// Problem constants
#define B_   2048
#define V_   3
#define K_   32
#define DIN_ 256
#define H_   8
#define DH_  64
#define REP_ 512

typedef unsigned short u16;
typedef unsigned int   u32;
typedef __bf16 bf8 __attribute__((ext_vector_type(8)));
typedef float  f4  __attribute__((ext_vector_type(4)));

static __device__ __forceinline__ u16 f2bf(float f) {
  union { float f; u32 i; } x; x.f = f;
  u32 r = (x.i + 0x7FFFu + ((x.i >> 16) & 1u)) >> 16;   // RNE
  return (u16)r;
}
static __device__ __forceinline__ float bf2f(u16 u) {
  union { u32 i; float f; } x; x.i = ((u32)u) << 16;
  return x.f;
}
static __device__ __forceinline__ float bflo(u32 q) {
  union { u32 i; float f; } x; x.i = q << 16; return x.f;
}
static __device__ __forceinline__ float bfhi(u32 q) {
  union { u32 i; float f; } x; x.i = q & 0xffff0000u; return x.f;
}

// async global->LDS DMA, 16 B per lane; lane i lands at base + i*16
static __device__ __forceinline__ void gl2lds16(const u16* g, u16* l) {
  __builtin_amdgcn_global_load_lds(
      (const __attribute__((address_space(1))) unsigned int*)(g),
      (__attribute__((address_space(3))) unsigned int*)(l), 16, 0, 0);
}

// ---------------------------------------------------------------------------
// K0: weight prep.
//  nWt/aWt: [v][kt(8)] x 32KB "LDS image": element at hw index
//    n*32 + (c ^ ((n>>1)&3))*8 + m   equals  W[k = kt*32 + c*8 + m][n]  (bf16)
//  Wvt: [v][h][e(64)][d(64)] bf16 (transposed: B-operand layout)
// ---------------------------------------------------------------------------
__global__ __launch_bounds__(256) void k0_prep(
    const float* __restrict__ nW, const float* __restrict__ aW,
    const float* __restrict__ Wv,
    u16* __restrict__ nWt, u16* __restrict__ aWt,
    u16* __restrict__ Wvt)
{
  int id = blockIdx.x * 256 + threadIdx.x;
  if (id < 393216) {                       // 3*8*512*32
    int v  = id / 131072, r  = id % 131072;
    int kt = r / 16384,   r2 = r % 16384;
    int n  = r2 >> 5;
    int s  = (r2 >> 3) & 3;
    int m  = r2 & 7;
    int c  = s ^ ((n >> 1) & 3);
    int k  = kt * 32 + c * 8 + m;
    int src = (v * 256 + k) * 512 + n;
    nWt[id] = f2bf(nW[src]);
    aWt[id] = f2bf(aW[src]);
  } else {
    int j = id - 393216;                   // < 98304 = 3*8*64*64
    int vh = j / 4096, r = j % 4096;
    int e = r / 64, d = r % 64;
    int src = (vh * 64 + d) * 64 + e;
    Wvt[j] = f2bf(Wv[src]);
  }
}

// ---------------------------------------------------------------------------
// K0b: Wqk[vh][d][e] = sum_c Wq[vh][d][c] * Wk[vh][e][c]   (fp32)
// ---------------------------------------------------------------------------
__global__ __launch_bounds__(256) void k0_wqk(
    const float* __restrict__ Wq, const float* __restrict__ Wk,
    float* __restrict__ Wqk)
{
  int vh = blockIdx.x, t = threadIdx.x;
  __shared__ float wq[4096], wkT[4096];
  #pragma unroll
  for (int i = 0; i < 16; ++i) {
    int idx = i * 256 + t;
    wq[idx] = Wq[(long)vh * 4096 + idx];
    int e = idx >> 6, c = idx & 63;
    wkT[c * 64 + e] = Wk[(long)vh * 4096 + e * 64 + c];
  }
  __syncthreads();
  int d = t >> 2, e0 = (t & 3) * 16;
  float acc[16];
  #pragma unroll
  for (int j = 0; j < 16; ++j) acc[j] = 0.f;
  for (int c = 0; c < 64; ++c) {
    float a = wq[d * 64 + c];
    const float* wr = &wkT[c * 64 + e0];
    #pragma unroll
    for (int j = 0; j < 16; ++j) acc[j] += a * wr[j];
  }
  #pragma unroll
  for (int j = 0; j < 16; ++j) Wqk[(long)vh * 4096 + d * 64 + e0 + j] = acc[j];
}

// ---------------------------------------------------------------------------
// K1 (anchor only now): [64 x 512] = [64 x 256] @ [256 x 512] bf16 MFMA GEMM
// + bias + LN.  mode 1: block = 64 b's for one v; out ha fp32 [b][v][512].
// (mode 0 path retained but unused.)
// ---------------------------------------------------------------------------
union K1Smem {
  struct { u16 A[64 * 256]; u16 B[16384]; } p;   // 32 KB + 32 KB
  u16 S[64 * 512];                               // 64 KB (epilogue)
};

__global__ __launch_bounds__(512, 4) void k1_gemm_ln(
    const float* __restrict__ X,
    const u16*   __restrict__ Wt,
    const float* __restrict__ bias,
    const float* __restrict__ gamma,
    const float* __restrict__ betap,
    u16*   __restrict__ hn,
    float* __restrict__ ha,
    int mode, int b0, int Bc)
{
  __shared__ K1Smem sm;
  const int v = blockIdx.y, blk = blockIdx.x, t = threadIdx.x;
  const int w = t >> 6, l = t & 63, lm = l & 15, lg = l >> 4;
  const int wm = w & 1, wn = w >> 1;

  float bcol[8];
  #pragma unroll
  for (int tn = 0; tn < 8; ++tn) bcol[tn] = bias[v * 512 + wn * 128 + tn * 16 + lm];

  {
    int row = t >> 3;
    int cbase = (t & 7) * 32;
    long grow;
    if (mode == 0) { int b = b0 + blk * 2 + (row >> 5); grow = ((long)(b * 3 + v) * 32 + (row & 31)) * 256; }
    else           { int b = blk * 64 + row;            grow = (long)(b * 3 + v) * 256; }
    const float4* src = (const float4*)(X + grow + cbase);
    int sw = row & 7;
    #pragma unroll
    for (int j = 0; j < 8; ++j) {
      float4 f = src[j];
      int col = cbase + j * 4;
      int c = col >> 3, m = col & 7;
      ushort4 u;
      u.x = f2bf(f.x); u.y = f2bf(f.y); u.z = f2bf(f.z); u.w = f2bf(f.w);
      *(ushort4*)&sm.p.A[row * 256 + ((c ^ sw) << 3) + m] = u;
    }
  }

  f4 acc[2][8];
  #pragma unroll
  for (int i = 0; i < 2; ++i)
    #pragma unroll
    for (int j = 0; j < 8; ++j) { f4 z = {0.f, 0.f, 0.f, 0.f}; acc[i][j] = z; }

  const u16* Wbase = Wt + (long)v * 8 * 16384;
  for (int kt = 0; kt < 8; ++kt) {
    __syncthreads();
    {
      const u16* gp = Wbase + (long)kt * 16384 + t * 8;
      u16* lp = &sm.p.B[t * 8];
      #pragma unroll
      for (int r = 0; r < 4; ++r) gl2lds16(gp + r * 4096, lp + r * 4096);
    }
    __syncthreads();
    bf8 af[2];
    #pragma unroll
    for (int tm = 0; tm < 2; ++tm) {
      int row = wm * 32 + tm * 16 + lm;
      int c = kt * 4 + lg;
      af[tm] = *(const bf8*)&sm.p.A[row * 256 + ((c ^ (row & 7)) << 3)];
    }
    #pragma unroll
    for (int tn = 0; tn < 8; ++tn) {
      int n = wn * 128 + tn * 16 + lm;
      bf8 bv = *(const bf8*)&sm.p.B[n * 32 + ((lg ^ ((n >> 1) & 3)) << 3)];
      acc[0][tn] = __builtin_amdgcn_mfma_f32_16x16x32_bf16(af[0], bv, acc[0][tn], 0, 0, 0);
      acc[1][tn] = __builtin_amdgcn_mfma_f32_16x16x32_bf16(af[1], bv, acc[1][tn], 0, 0, 0);
    }
  }
  __syncthreads();

  #pragma unroll
  for (int tm = 0; tm < 2; ++tm)
    #pragma unroll
    for (int tn = 0; tn < 8; ++tn) {
      int col = wn * 128 + tn * 16 + lm;
      int c = col >> 3, m = col & 7;
      #pragma unroll
      for (int r = 0; r < 4; ++r) {
        int row = wm * 32 + tm * 16 + lg * 4 + r;
        sm.S[row * 512 + ((c ^ (row & 7)) << 3) + m] = f2bf(acc[tm][tn][r] + bcol[tn]);
      }
    }
  __syncthreads();

  {
    int row = t >> 3, ch = t & 7, sw = row & 7;
    float s1 = 0.f, s2 = 0.f;
    #pragma unroll
    for (int j = 0; j < 8; ++j) {
      int c = j * 8 + ch;
      uint4 q = *(const uint4*)&sm.S[row * 512 + ((c ^ sw) << 3)];
      float x0 = bflo(q.x), x1 = bfhi(q.x), x2 = bflo(q.y), x3 = bfhi(q.y);
      float x4 = bflo(q.z), x5 = bfhi(q.z), x6 = bflo(q.w), x7 = bfhi(q.w);
      s1 += ((x0 + x1) + (x2 + x3)) + ((x4 + x5) + (x6 + x7));
      s2 += ((x0*x0 + x1*x1) + (x2*x2 + x3*x3)) + ((x4*x4 + x5*x5) + (x6*x6 + x7*x7));
    }
    #pragma unroll
    for (int d = 1; d < 8; d <<= 1) { s1 += __shfl_xor(s1, d, 64); s2 += __shfl_xor(s2, d, 64); }
    float mu = s1 * (1.f / 512.f);
    float var = s2 * (1.f / 512.f) - mu * mu;
    float rs = rsqrtf(var + 1e-5f);
    #pragma unroll
    for (int j = 0; j < 8; ++j) {
      int c = j * 8 + ch;
      uint4 q = *(const uint4*)&sm.S[row * 512 + ((c ^ sw) << 3)];
      int col0 = c * 8;
      float4 g0 = *(const float4*)&gamma[v * 512 + col0];
      float4 g1 = *(const float4*)&gamma[v * 512 + col0 + 4];
      float4 e0 = *(const float4*)&betap[v * 512 + col0];
      float4 e1 = *(const float4*)&betap[v * 512 + col0 + 4];
      float y0 = (bflo(q.x) - mu) * rs * g0.x + e0.x;
      float y1 = (bfhi(q.x) - mu) * rs * g0.y + e0.y;
      float y2 = (bflo(q.y) - mu) * rs * g0.z + e0.z;
      float y3 = (bfhi(q.y) - mu) * rs * g0.w + e0.w;
      float y4 = (bflo(q.z) - mu) * rs * g1.x + e1.x;
      float y5 = (bfhi(q.z) - mu) * rs * g1.y + e1.y;
      float y6 = (bflo(q.w) - mu) * rs * g1.z + e1.z;
      float y7 = (bfhi(q.w) - mu) * rs * g1.w + e1.w;
      if (mode == 0) {
        uint4 q4;
        q4.x = (u32)f2bf(y0) | ((u32)f2bf(y1) << 16);
        q4.y = (u32)f2bf(y2) | ((u32)f2bf(y3) << 16);
        q4.z = (u32)f2bf(y4) | ((u32)f2bf(y5) << 16);
        q4.w = (u32)f2bf(y6) | ((u32)f2bf(y7) << 16);
        int bl_ = blk * 2 + (row >> 5), krow = row & 31;
        u16* dst = hn + (((long)(v * 8 + j) * Bc + bl_) * 32 + krow) * 64 + ch * 8;
        *(uint4*)dst = q4;
      } else {
        int b = blk * 64 + row;
        float* dst = ha + (long)(b * 3 + v) * 512 + col0;
        float4 w0, w1;
        w0.x = y0; w0.y = y1; w0.z = y2; w0.w = y3;
        w1.x = y4; w1.y = y5; w1.z = y6; w1.w = y7;
        *(float4*)dst = w0;
        *(float4*)(dst + 4) = w1;
      }
    }
  }
}

// ---------------------------------------------------------------------------
// K12: FUSED neighbor encoder + per-view attention.
// Block = 2 b's x 1 v (all 8 heads).  Grid (B/2, 3), 512 threads.
// Phase 1: GEMM+bias -> S (k1 mode-0 core, unchanged).
// Phase 2: LN in place in S (bf16, same rounding as the old hn path).
// Phase 3: t = ha@Wqk*0.125 ; scores = t . hn (from S) + geom*log(ew);
//          softmax ; V-proj MFMA (A from S, B = Wvt from global) ;
//          o = attn@V ; out = o@Wo + ha ; write vt.
// Eliminates the 100MB hn HBM write + 100MB read and all of k2.
// ---------------------------------------------------------------------------
__global__ __launch_bounds__(512, 4) void k12_fused(
    const float* __restrict__ X,      // x_neighbors
    const u16*   __restrict__ Wt,     // nWt (swizzled LDS-image tiles)
    const float* __restrict__ bias,   // nb
    const float* __restrict__ gamma,  // ng
    const float* __restrict__ betap,  // nbeta
    const float* __restrict__ ha,     // [B][V][512] f32
    const u16*   __restrict__ Wvt,    // [V][H][64][64] bf16 transposed
    const float* __restrict__ Wqk,    // [V][H][64][64] f32 (folded Wq Wk^T)
    const float* __restrict__ Wo,     // [V][H][64][64] f32
    const float* __restrict__ ew,     // [B][V][K]
    const float* __restrict__ gls,    // [V][H]
    float* __restrict__ vt)           // [B][H][V][64]
{
  __shared__ K1Smem sm;
  __shared__ float tS[1024];     // [2b][8h][64e]
  __shared__ float aS[512];      // [2b][8h][32k]
  __shared__ float oS[1024];     // [2b][8h][64d]
  __shared__ float haS[1024];    // [2b][512]

  const int v = blockIdx.y, blk = blockIdx.x, t = threadIdx.x;
  const int w = t >> 6, l = t & 63, lm = l & 15, lg = l >> 4;
  const int wm = w & 1, wn = w >> 1;

  float bcol[8];
  #pragma unroll
  for (int tn = 0; tn < 8; ++tn) bcol[tn] = bias[v * 512 + wn * 128 + tn * 16 + lm];

  // ---- stage A once (fp32 -> bf16, XOR-swizzled rows): 2 b's x 32 k ----
  {
    int row = t >> 3;
    int cbase = (t & 7) * 32;
    int b = blk * 2 + (row >> 5);
    long grow = ((long)(b * 3 + v) * 32 + (row & 31)) * 256;
    const float4* src = (const float4*)(X + grow + cbase);
    int sw = row & 7;
    #pragma unroll
    for (int j = 0; j < 8; ++j) {
      float4 f = src[j];
      int col = cbase + j * 4;
      int c = col >> 3, m = col & 7;
      ushort4 u;
      u.x = f2bf(f.x); u.y = f2bf(f.y); u.z = f2bf(f.z); u.w = f2bf(f.w);
      *(ushort4*)&sm.p.A[row * 256 + ((c ^ sw) << 3) + m] = u;
    }
  }
  // ---- stage ha slice for both b's (2 x 512 f32) ----
  {
    int b = t >> 8, e = (t & 255) * 2;
    *(float2*)&haS[b * 512 + e] =
        *(const float2*)&ha[((long)(blk * 2 + b) * 3 + v) * 512 + e];
  }

  f4 acc[2][8];
  #pragma unroll
  for (int i = 0; i < 2; ++i)
    #pragma unroll
    for (int j = 0; j < 8; ++j) { f4 z = {0.f, 0.f, 0.f, 0.f}; acc[i][j] = z; }

  // ---- K loop: 2 barriers/kt, B via async DMA ----
  const u16* Wbase = Wt + (long)v * 8 * 16384;
  for (int kt = 0; kt < 8; ++kt) {
    __syncthreads();
    {
      const u16* gp = Wbase + (long)kt * 16384 + t * 8;
      u16* lp = &sm.p.B[t * 8];
      #pragma unroll
      for (int r = 0; r < 4; ++r) gl2lds16(gp + r * 4096, lp + r * 4096);
    }
    __syncthreads();
    bf8 af[2];
    #pragma unroll
    for (int tm = 0; tm < 2; ++tm) {
      int row = wm * 32 + tm * 16 + lm;
      int c = kt * 4 + lg;
      af[tm] = *(const bf8*)&sm.p.A[row * 256 + ((c ^ (row & 7)) << 3)];
    }
    #pragma unroll
    for (int tn = 0; tn < 8; ++tn) {
      int n = wn * 128 + tn * 16 + lm;
      bf8 bv = *(const bf8*)&sm.p.B[n * 32 + ((lg ^ ((n >> 1) & 3)) << 3)];
      acc[0][tn] = __builtin_amdgcn_mfma_f32_16x16x32_bf16(af[0], bv, acc[0][tn], 0, 0, 0);
      acc[1][tn] = __builtin_amdgcn_mfma_f32_16x16x32_bf16(af[1], bv, acc[1][tn], 0, 0, 0);
    }
  }
  __syncthreads();

  // ---- dump z = acc + bias into S (64x512 bf16, XOR-swizzled) ----
  #pragma unroll
  for (int tm = 0; tm < 2; ++tm)
    #pragma unroll
    for (int tn = 0; tn < 8; ++tn) {
      int col = wn * 128 + tn * 16 + lm;
      int c = col >> 3, m = col & 7;
      #pragma unroll
      for (int r = 0; r < 4; ++r) {
        int row = wm * 32 + tm * 16 + lg * 4 + r;
        sm.S[row * 512 + ((c ^ (row & 7)) << 3) + m] = f2bf(acc[tm][tn][r] + bcol[tn]);
      }
    }
  __syncthreads();

  // ---- LayerNorm in place (8 threads/row), then t = ha@Wqk*0.125 ----
  {
    int row = t >> 3, ch = t & 7, sw = row & 7;
    float s1 = 0.f, s2 = 0.f;
    #pragma unroll
    for (int j = 0; j < 8; ++j) {
      int c = j * 8 + ch;
      uint4 q = *(const uint4*)&sm.S[row * 512 + ((c ^ sw) << 3)];
      float x0 = bflo(q.x), x1 = bfhi(q.x), x2 = bflo(q.y), x3 = bfhi(q.y);
      float x4 = bflo(q.z), x5 = bfhi(q.z), x6 = bflo(q.w), x7 = bfhi(q.w);
      s1 += ((x0 + x1) + (x2 + x3)) + ((x4 + x5) + (x6 + x7));
      s2 += ((x0*x0 + x1*x1) + (x2*x2 + x3*x3)) + ((x4*x4 + x5*x5) + (x6*x6 + x7*x7));
    }
    #pragma unroll
    for (int d = 1; d < 8; d <<= 1) { s1 += __shfl_xor(s1, d, 64); s2 += __shfl_xor(s2, d, 64); }
    float mu = s1 * (1.f / 512.f);
    float var = s2 * (1.f / 512.f) - mu * mu;
    float rs = rsqrtf(var + 1e-5f);
    #pragma unroll
    for (int j = 0; j < 8; ++j) {
      int c = j * 8 + ch;
      u16* sp = &sm.S[row * 512 + ((c ^ sw) << 3)];
      uint4 q = *(const uint4*)sp;
      int col0 = c * 8;
      float4 g0 = *(const float4*)&gamma[v * 512 + col0];
      float4 g1 = *(const float4*)&gamma[v * 512 + col0 + 4];
      float4 e0 = *(const float4*)&betap[v * 512 + col0];
      float4 e1 = *(const float4*)&betap[v * 512 + col0 + 4];
      float y0 = (bflo(q.x) - mu) * rs * g0.x + e0.x;
      float y1 = (bfhi(q.x) - mu) * rs * g0.y + e0.y;
      float y2 = (bflo(q.y) - mu) * rs * g0.z + e0.z;
      float y3 = (bfhi(q.y) - mu) * rs * g0.w + e0.w;
      float y4 = (bflo(q.z) - mu) * rs * g1.x + e1.x;
      float y5 = (bfhi(q.z) - mu) * rs * g1.y + e1.y;
      float y6 = (bflo(q.w) - mu) * rs * g1.z + e1.z;
      float y7 = (bfhi(q.w) - mu) * rs * g1.w + e1.w;
      uint4 q4;
      q4.x = (u32)f2bf(y0) | ((u32)f2bf(y1) << 16);
      q4.y = (u32)f2bf(y2) | ((u32)f2bf(y3) << 16);
      q4.z = (u32)f2bf(y4) | ((u32)f2bf(y5) << 16);
      q4.w = (u32)f2bf(y6) | ((u32)f2bf(y7) << 16);
      *(uint4*)sp = q4;                     // hn, bit-identical to old path
    }
  }
  // t_s: thread = (h,e); loop over b so Wqk is read once, used twice
  {
    int h = t >> 6, e = t & 63;
    const float* wq = Wqk + (long)(v * 8 + h) * 4096;
    float a0 = 0.f, a1 = 0.f;
    const float* h0 = &haS[h * 64];
    const float* h1 = &haS[512 + h * 64];
    for (int d = 0; d < 64; ++d) {
      float wv = wq[d * 64 + e];
      a0 += h0[d] * wv;
      a1 += h1[d] * wv;
    }
    tS[h * 64 + e]       = a0 * 0.125f;
    tS[512 + h * 64 + e] = a1 * 0.125f;
  }
  __syncthreads();

  // ---- scores + softmax: thread = (b,h,k), 2*8*32 = 512 ----
  {
    int b = t >> 8, h = (t >> 5) & 7, k = t & 31;
    float x = gls[v * 8 + h];
    float gsc = (x > 20.f) ? x : log1pf(expf(x));
    int r = b * 32 + k, sw = r & 7;
    const float* tb = &tS[(b * 8 + h) * 64];
    float s = 0.f;
    #pragma unroll
    for (int j = 0; j < 8; ++j) {
      int c8 = h * 8 + j;
      uint4 q = *(const uint4*)&sm.S[r * 512 + ((c8 ^ sw) << 3)];
      const float* tj = tb + j * 8;
      s += tj[0] * bflo(q.x) + tj[1] * bfhi(q.x)
         + tj[2] * bflo(q.y) + tj[3] * bfhi(q.y)
         + tj[4] * bflo(q.z) + tj[5] * bfhi(q.z)
         + tj[6] * bflo(q.w) + tj[7] * bfhi(q.w);
    }
    float e_w = ew[((long)(blk * 2 + b) * 3 + v) * 32 + k];
    s += gsc * logf(e_w + 1e-6f);
    float m = s;
    #pragma unroll
    for (int d = 1; d < 32; d <<= 1) m = fmaxf(m, __shfl_xor(m, d, 64));
    float exs = expf(s - m), sum = exs;
    #pragma unroll
    for (int d = 1; d < 32; d <<= 1) sum += __shfl_xor(sum, d, 64);
    aS[(b * 8 + h) * 32 + k] = exs / sum;
  }
  __syncthreads();

  // ---- per wave: 2 (b,h) pairs: V-proj MFMA from S + o = attn@V ----
  for (int i = 0; i < 2; ++i) {
    int p = w * 2 + i, b = p >> 3, h = p & 7;
    const u16* wvg = Wvt + (long)(v * 8 + h) * 4096;
    f4 aV[2][4];
    #pragma unroll
    for (int a = 0; a < 2; ++a)
      #pragma unroll
      for (int j = 0; j < 4; ++j) { f4 z = {0.f, 0.f, 0.f, 0.f}; aV[a][j] = z; }
    #pragma unroll
    for (int ks = 0; ks < 2; ++ks) {
      int ko = ks * 32 + lg * 8;
      bf8 af[2];
      #pragma unroll
      for (int tm = 0; tm < 2; ++tm) {
        int r = b * 32 + tm * 16 + lm;
        int c8 = h * 8 + ks * 4 + lg;
        af[tm] = *(const bf8*)&sm.S[r * 512 + ((c8 ^ (r & 7)) << 3)];
      }
      #pragma unroll
      for (int tn = 0; tn < 4; ++tn) {
        bf8 bv = *(const bf8*)&wvg[(tn * 16 + lm) * 64 + ko];
        #pragma unroll
        for (int tm = 0; tm < 2; ++tm)
          aV[tm][tn] = __builtin_amdgcn_mfma_f32_16x16x32_bf16(af[tm], bv, aV[tm][tn], 0, 0, 0);
      }
    }
    float pp[4] = {0.f, 0.f, 0.f, 0.f};
    #pragma unroll
    for (int tm = 0; tm < 2; ++tm)
      #pragma unroll
      for (int r4 = 0; r4 < 4; ++r4) {
        int k = tm * 16 + lg * 4 + r4;
        float a = aS[p * 32 + k];
        #pragma unroll
        for (int tn = 0; tn < 4; ++tn) pp[tn] += a * aV[tm][tn][r4];
      }
    #pragma unroll
    for (int tn = 0; tn < 4; ++tn) {
      float x = pp[tn];
      x += __shfl_xor(x, 16, 64);
      x += __shfl_xor(x, 32, 64);
      if (l < 16) oS[p * 64 + tn * 16 + lm] = x;
    }
  }
  __syncthreads();

  // ---- out = o @ Wo + ha (residual); thread = (h,e), loop over b ----
  {
    int h = t >> 6, e = t & 63;
    const float* wo = Wo + (long)(v * 8 + h) * 4096;
    float a0 = haS[h * 64 + e];
    float a1 = haS[512 + h * 64 + e];
    const float* o0 = &oS[h * 64];
    const float* o1 = &oS[512 + h * 64];
    for (int d = 0; d < 64; ++d) {
      float wv = wo[d * 64 + e];
      a0 += o0[d] * wv;
      a1 += o1[d] * wv;
    }
    vt[(((long)(blk * 2 + 0) * 8 + h) * 3 + v) * 64 + e] = a0;
    vt[(((long)(blk * 2 + 1) * 8 + h) * 3 + v) * 64 + e] = a1;
  }
}

// ---------------------------------------------------------------------------
// K3: router MLP (fp32). Block = 4 b's (512 blocks -> full GPU).
// ---------------------------------------------------------------------------
__global__ __launch_bounds__(256) void k3_router(
    const float* __restrict__ g, const float* __restrict__ rW1, const float* __restrict__ rb1,
    const float* __restrict__ rW2, const float* __restrict__ rb2,
    const float* __restrict__ vW, const float* __restrict__ vb,
    const float* __restrict__ mW, const float* __restrict__ mb,
    const float* __restrict__ gW, const float* __restrict__ gb,
    float* __restrict__ pi, float* __restrict__ beta_o, float* __restrict__ gate_o)
{
  __shared__ float gs[4 * 128], h1[4 * 256], h2[4 * 256], lgt[4 * 40];
  int t = threadIdx.x, bb = blockIdx.x * 4;
  #pragma unroll
  for (int r = 0; r < 2; ++r) { int idx = r * 256 + t; gs[idx] = g[(long)bb * 128 + idx]; }
  __syncthreads();
  {
    int bl = t >> 6, e0 = (t & 63) * 4;
    float acc[4];
    #pragma unroll
    for (int j = 0; j < 4; ++j) acc[j] = rb1[e0 + j];
    for (int i = 0; i < 128; ++i) {
      float gv = gs[bl * 128 + i];
      const float* wr = rW1 + i * 256 + e0;
      #pragma unroll
      for (int j = 0; j < 4; ++j) acc[j] += gv * wr[j];
    }
    #pragma unroll
    for (int j = 0; j < 4; ++j) { float x = acc[j]; h1[bl * 256 + e0 + j] = 0.5f * x * (1.f + erff(x * 0.70710678118f)); }
  }
  __syncthreads();
  {
    int bl = t >> 6, e0 = (t & 63) * 4;
    float acc[4];
    #pragma unroll
    for (int j = 0; j < 4; ++j) acc[j] = rb2[e0 + j];
    for (int i = 0; i < 256; ++i) {
      float hv = h1[bl * 256 + i];
      const float* wr = rW2 + i * 256 + e0;
      #pragma unroll
      for (int j = 0; j < 4; ++j) acc[j] += hv * wr[j];
    }
    #pragma unroll
    for (int j = 0; j < 4; ++j) { float x = acc[j]; h2[bl * 256 + e0 + j] = 0.5f * x * (1.f + erff(x * 0.70710678118f)); }
  }
  __syncthreads();
  if (t < 160) {
    int bl = t / 40, j = t % 40;
    const float* W; float bs; int col, stride;
    if (j < 24)      { W = vW; col = j;      stride = 24; bs = vb[j]; }
    else if (j < 32) { W = mW; col = j - 24; stride = 8;  bs = mb[j - 24]; }
    else             { W = gW; col = j - 32; stride = 8;  bs = gb[j - 32]; }
    float acc = bs;
    for (int i = 0; i < 256; ++i) acc += h2[bl * 256 + i] * W[i * stride + col];
    lgt[bl * 40 + j] = acc;
  }
  __syncthreads();
  if (t < 4) {
    int b = bb + t;
    const float* L = &lgt[t * 40];
    #pragma unroll
    for (int hh = 0; hh < 8; ++hh) {
      float a0 = L[hh * 3], a1 = L[hh * 3 + 1], a2v = L[hh * 3 + 2];
      float m = fmaxf(a0, fmaxf(a1, a2v));
      float x0 = expf(a0 - m), x1 = expf(a1 - m), x2 = expf(a2v - m);
      float inv = 1.f / (x0 + x1 + x2);
      pi[b * 24 + hh * 3 + 0] = x0 * inv;
      pi[b * 24 + hh * 3 + 1] = x1 * inv;
      pi[b * 24 + hh * 3 + 2] = x2 * inv;
      beta_o[b * 8 + hh] = 1.f / (1.f + expf(-L[24 + hh]));
    }
    float m = L[32];
    #pragma unroll
    for (int hh = 1; hh < 8; ++hh) m = fmaxf(m, L[32 + hh]);
    float s = 0.f, ex[8];
    #pragma unroll
    for (int hh = 0; hh < 8; ++hh) { ex[hh] = expf(L[32 + hh] - m); s += ex[hh]; }
    float inv = 1.f / s;
    #pragma unroll
    for (int hh = 0; hh < 8; ++hh) gate_o[b * 8 + hh] = ex[hh] * inv;
  }
}

// ---------------------------------------------------------------------------
// K4: pi-mixture + cross-view attention + output. Block = 4 b's, fp32.
// ---------------------------------------------------------------------------
__global__ __launch_bounds__(256) void k4_cross(
    const float* __restrict__ vtg, const float* __restrict__ pig,
    const float* __restrict__ betag, const float* __restrict__ gateg,
    const float* __restrict__ cWq, const float* __restrict__ cWk,
    const float* __restrict__ cWv, const float* __restrict__ cWo,
    float* __restrict__ out)
{
  __shared__ float smem[12544];
  float* vts   = smem;          // 6144: [4][8][3][64]
  float* mixs  = smem + 6144;   // 2048
  float* buf1  = smem + 8192;   // 2048: qc, then y
  float* buf2  = smem + 10240;  // 2048: w,  then cr
  float* a2s   = smem + 12288;  // 96
  float* pis   = smem + 12384;  // 96
  float* betas = smem + 12480;  // 32
  float* gates = smem + 12512;  // 32

  int t = threadIdx.x, bblk = blockIdx.x * 4;
  {
    const float4* src = (const float4*)(vtg + (long)bblk * 1536);
    #pragma unroll
    for (int r = 0; r < 6; ++r) ((float4*)vts)[r * 256 + t] = src[r * 256 + t];
    if (t < 96) pis[t] = pig[bblk * 24 + t];
    if (t < 32) { betas[t] = betag[bblk * 8 + t]; gates[t] = gateg[bblk * 8 + t]; }
  }
  __syncthreads();
  int bl = t >> 6, hh = (t >> 3) & 7, e0 = (t & 7) * 8;
  const float* vbh = &vts[(bl * 8 + hh) * 192];
  {
    float p0 = pis[bl * 24 + hh * 3], p1 = pis[bl * 24 + hh * 3 + 1], p2 = pis[bl * 24 + hh * 3 + 2];
    #pragma unroll
    for (int j = 0; j < 8; ++j) {
      int e = e0 + j;
      mixs[(bl * 8 + hh) * 64 + e] = p0 * vbh[e] + p1 * vbh[64 + e] + p2 * vbh[128 + e];
    }
  }
  __syncthreads();
  {
    float acc[8] = {0.f,0.f,0.f,0.f,0.f,0.f,0.f,0.f};
    const float* M = &mixs[(bl * 8 + hh) * 64];
    for (int d = 0; d < 64; ++d) {
      float mv = M[d];
      const float* wr = &cWq[(hh * 64 + d) * 64 + e0];
      #pragma unroll
      for (int j = 0; j < 8; ++j) acc[j] += mv * wr[j];
    }
    #pragma unroll
    for (int j = 0; j < 8; ++j) buf1[(bl * 8 + hh) * 64 + e0 + j] = acc[j] * 0.125f;
  }
  __syncthreads();
  {
    const float* Q = &buf1[(bl * 8 + hh) * 64];
    #pragma unroll
    for (int d2 = 0; d2 < 8; ++d2) {
      const float* wr = &cWk[(hh * 64 + e0 + d2) * 64];
      float a = 0.f;
      for (int e = 0; e < 64; ++e) a += wr[e] * Q[e];
      buf2[(bl * 8 + hh) * 64 + e0 + d2] = a;
    }
  }
  __syncthreads();
  if (t < 32) {
    int b2 = t >> 3, h2 = t & 7;
    const float* Wd = &buf2[(b2 * 8 + h2) * 64];
    const float* vb2 = &vts[(b2 * 8 + h2) * 192];
    float s[3];
    #pragma unroll
    for (int v3 = 0; v3 < 3; ++v3) {
      float a = 0.f;
      for (int d = 0; d < 64; ++d) a += Wd[d] * vb2[v3 * 64 + d];
      s[v3] = a + logf(pis[b2 * 24 + h2 * 3 + v3] + 1e-6f);
    }
    float m = fmaxf(s[0], fmaxf(s[1], s[2]));
    float x0 = expf(s[0] - m), x1 = expf(s[1] - m), x2 = expf(s[2] - m);
    float inv = 1.f / (x0 + x1 + x2);
    a2s[(b2 * 8 + h2) * 3 + 0] = x0 * inv;
    a2s[(b2 * 8 + h2) * 3 + 1] = x1 * inv;
    a2s[(b2 * 8 + h2) * 3 + 2] = x2 * inv;
  }
  __syncthreads();
  {
    float a0 = a2s[(bl * 8 + hh) * 3], a1 = a2s[(bl * 8 + hh) * 3 + 1], a2v = a2s[(bl * 8 + hh) * 3 + 2];
    #pragma unroll
    for (int j = 0; j < 8; ++j) {
      int e = e0 + j;
      buf1[(bl * 8 + hh) * 64 + e] = a0 * vbh[e] + a1 * vbh[64 + e] + a2v * vbh[128 + e];
    }
  }
  __syncthreads();
  {
    float acc[8] = {0.f,0.f,0.f,0.f,0.f,0.f,0.f,0.f};
    const float* Y = &buf1[(bl * 8 + hh) * 64];
    for (int d = 0; d < 64; ++d) {
      float yv = Y[d];
      const float* wr = &cWv[(hh * 64 + d) * 64 + e0];
      #pragma unroll
      for (int j = 0; j < 8; ++j) acc[j] += yv * wr[j];
    }
    #pragma unroll
    for (int j = 0; j < 8; ++j) buf2[(bl * 8 + hh) * 64 + e0 + j] = acc[j];
  }
  __syncthreads();
  {
    float acc[8] = {0.f,0.f,0.f,0.f,0.f,0.f,0.f,0.f};
    const float* C2 = &buf2[(bl * 8 + hh) * 64];
    for (int d = 0; d < 64; ++d) {
      float cv = C2[d];
      const float* wr = &cWo[(hh * 64 + d) * 64 + e0];
      #pragma unroll
      for (int j = 0; j < 8; ++j) acc[j] += cv * wr[j];
    }
    float bt = betas[bl * 8 + hh], gt = gates[bl * 8 + hh];
    const float* M = &mixs[(bl * 8 + hh) * 64];
    #pragma unroll
    for (int j = 0; j < 8; ++j)
      out[((long)(bblk + bl) * 8 + hh) * 64 + e0 + j] = gt * (bt * acc[j] + (1.f - bt) * M[e0 + j]);
  }
}

// ---------------------------------------------------------------------------
extern "C" void kernel_launch(void* const* d_in, const int* in_sizes, int n_in,
                              void* d_out, int out_size, void* d_ws, size_t ws_size,
                              hipStream_t stream) {
  const float* x_anchor    = (const float*)d_in[0];
  const float* x_neighbors = (const float*)d_in[1];
  const float* edge_w      = (const float*)d_in[2];
  const float* g           = (const float*)d_in[3];
  const float* aW  = (const float*)d_in[4];
  const float* ab  = (const float*)d_in[5];
  const float* ag  = (const float*)d_in[6];
  const float* abeta = (const float*)d_in[7];
  const float* nW  = (const float*)d_in[8];
  const float* nb  = (const float*)d_in[9];
  const float* ng  = (const float*)d_in[10];
  const float* nbeta = (const float*)d_in[11];
  const float* Wq  = (const float*)d_in[12];
  const float* Wk  = (const float*)d_in[13];
  const float* Wv  = (const float*)d_in[14];
  const float* Wo  = (const float*)d_in[15];
  const float* gls = (const float*)d_in[16];
  const float* cWq = (const float*)d_in[17];
  const float* cWk = (const float*)d_in[18];
  const float* cWv = (const float*)d_in[19];
  const float* cWo = (const float*)d_in[20];
  const float* rW1 = (const float*)d_in[21];
  const float* rb1 = (const float*)d_in[22];
  const float* rW2 = (const float*)d_in[23];
  const float* rb2 = (const float*)d_in[24];
  const float* vW  = (const float*)d_in[25];
  const float* vb  = (const float*)d_in[26];
  const float* mW  = (const float*)d_in[27];
  const float* mb  = (const float*)d_in[28];
  const float* gW  = (const float*)d_in[29];
  const float* gb  = (const float*)d_in[30];

  // workspace carve-up (hn intermediate eliminated by fusion -> no chunking)
  char* p = (char*)d_ws;
  u16* nWt = (u16*)p;  p += 786432;
  u16* aWt = (u16*)p;  p += 786432;
  u16* Wvt = (u16*)p;  p += 196608;
  float* WqkB = (float*)p; p += 393216;
  float* ha   = (float*)p; p += 12582912;
  float* vtb  = (float*)p; p += 12582912;
  float* pib  = (float*)p; p += 196608;
  float* betb = (float*)p; p += 65536;
  float* gatb = (float*)p; p += 65536;
  (void)ws_size;

  k0_prep<<<1920, 256, 0, stream>>>(nW, aW, Wv, nWt, aWt, Wvt);
  k0_wqk<<<24, 256, 0, stream>>>(Wq, Wk, WqkB);
  // anchor encoder: ha (fp32)
  k1_gemm_ln<<<dim3(32, 3), 512, 0, stream>>>(x_anchor, aWt, ab, ag, abeta,
                                              (u16*)nullptr, ha, 1, 0, 2048);
  k3_router<<<512, 256, 0, stream>>>(g, rW1, rb1, rW2, rb2, vW, vb, mW, mb, gW, gb,
                                     pib, betb, gatb);
  // fused neighbor encoder + per-view attention (single pass over B)
  k12_fused<<<dim3(1024, 3), 512, 0, stream>>>(x_neighbors, nWt, nb, ng, nbeta,
                                               ha, Wvt, WqkB, Wo, edge_w, gls, vtb);
  k4_cross<<<512, 256, 0, stream>>>(vtb, pib, betb, gatb, cWq, cWk, cWv, cWo,
                                    (float*)d_out);
}

// Round 2
// 766.956 us; speedup vs baseline: 1.0637x; 1.0637x over previous
//
#include <hip/hip_runtime.h>

// Problem constants
#define B_   2048
#define V_   3
#define K_   32
#define DIN_ 256
#define H_   8
#define DH_  64
#define REP_ 512

typedef unsigned short u16;
typedef unsigned int   u32;
typedef __bf16 bf8 __attribute__((ext_vector_type(8)));
typedef float  f4  __attribute__((ext_vector_type(4)));

static __device__ __forceinline__ u16 f2bf(float f) {
  union { float f; u32 i; } x; x.f = f;
  u32 r = (x.i + 0x7FFFu + ((x.i >> 16) & 1u)) >> 16;   // RNE
  return (u16)r;
}
static __device__ __forceinline__ float bf2f(u16 u) {
  union { u32 i; float f; } x; x.i = ((u32)u) << 16;
  return x.f;
}
static __device__ __forceinline__ float bflo(u32 q) {
  union { u32 i; float f; } x; x.i = q << 16; return x.f;
}
static __device__ __forceinline__ float bfhi(u32 q) {
  union { u32 i; float f; } x; x.i = q & 0xffff0000u; return x.f;
}

// async global->LDS DMA, 16 B per lane; lane i lands at base + i*16
static __device__ __forceinline__ void gl2lds16(const u16* g, u16* l) {
  __builtin_amdgcn_global_load_lds(
      (const __attribute__((address_space(1))) unsigned int*)(g),
      (__attribute__((address_space(3))) unsigned int*)(l), 16, 0, 0);
}

// ---------------------------------------------------------------------------
// K0: weight prep.
//  nWt/aWt: [v][kt(8)] x 32KB "LDS image": element at hw index
//    n*32 + (c ^ ((n>>1)&3))*8 + m   equals  W[k = kt*32 + c*8 + m][n]  (bf16)
//  Wvt: [v][h][e(64)][d(64)] bf16 (transposed: B-operand layout)
// ---------------------------------------------------------------------------
__global__ __launch_bounds__(256) void k0_prep(
    const float* __restrict__ nW, const float* __restrict__ aW,
    const float* __restrict__ Wv,
    u16* __restrict__ nWt, u16* __restrict__ aWt,
    u16* __restrict__ Wvt)
{
  int id = blockIdx.x * 256 + threadIdx.x;
  if (id < 393216) {                       // 3*8*512*32
    int v  = id / 131072, r  = id % 131072;
    int kt = r / 16384,   r2 = r % 16384;
    int n  = r2 >> 5;
    int s  = (r2 >> 3) & 3;
    int m  = r2 & 7;
    int c  = s ^ ((n >> 1) & 3);
    int k  = kt * 32 + c * 8 + m;
    int src = (v * 256 + k) * 512 + n;
    nWt[id] = f2bf(nW[src]);
    aWt[id] = f2bf(aW[src]);
  } else {
    int j = id - 393216;                   // < 98304 = 3*8*64*64
    int vh = j / 4096, r = j % 4096;
    int e = r / 64, d = r % 64;
    int src = (vh * 64 + d) * 64 + e;
    Wvt[j] = f2bf(Wv[src]);
  }
}

// ---------------------------------------------------------------------------
// K0b: Wqk[vh][d][e] = sum_c Wq[vh][d][c] * Wk[vh][e][c]   (fp32)
// ---------------------------------------------------------------------------
__global__ __launch_bounds__(256) void k0_wqk(
    const float* __restrict__ Wq, const float* __restrict__ Wk,
    float* __restrict__ Wqk)
{
  int vh = blockIdx.x, t = threadIdx.x;
  __shared__ float wq[4096], wkT[4096];
  #pragma unroll
  for (int i = 0; i < 16; ++i) {
    int idx = i * 256 + t;
    wq[idx] = Wq[(long)vh * 4096 + idx];
    int e = idx >> 6, c = idx & 63;
    wkT[c * 64 + e] = Wk[(long)vh * 4096 + e * 64 + c];
  }
  __syncthreads();
  int d = t >> 2, e0 = (t & 3) * 16;
  float acc[16];
  #pragma unroll
  for (int j = 0; j < 16; ++j) acc[j] = 0.f;
  for (int c = 0; c < 64; ++c) {
    float a = wq[d * 64 + c];
    const float* wr = &wkT[c * 64 + e0];
    #pragma unroll
    for (int j = 0; j < 16; ++j) acc[j] += a * wr[j];
  }
  #pragma unroll
  for (int j = 0; j < 16; ++j) Wqk[(long)vh * 4096 + d * 64 + e0 + j] = acc[j];
}

// ---------------------------------------------------------------------------
// K0c: tB[b][v][h][e] = 0.125 * sum_d ha[b][v][h*64+d] * Wqk[v][h][d][e]
// Hoisted out of k12 to keep k12 under the 128-reg/wave cap (round-1 spill).
// Block = one (b,v); 6144 blocks x 256 threads.
// ---------------------------------------------------------------------------
__global__ __launch_bounds__(256) void k_tq(
    const float* __restrict__ ha, const float* __restrict__ Wqk,
    float* __restrict__ tB)
{
  __shared__ float hs[512];
  int bv = blockIdx.x, t = threadIdx.x;
  int v = bv % 3;
  hs[t]       = ha[(long)bv * 512 + t];
  hs[256 + t] = ha[(long)bv * 512 + 256 + t];
  __syncthreads();
  int h = t >> 5, e0 = (t & 31) * 2;
  const float* wq = Wqk + ((long)v * 8 + h) * 4096 + e0;
  const float* hv = &hs[h * 64];
  float a0 = 0.f, a1 = 0.f;
  #pragma unroll 4
  for (int d = 0; d < 64; ++d) {
    float x = hv[d];
    float2 wv = *(const float2*)&wq[d * 64];
    a0 += x * wv.x;
    a1 += x * wv.y;
  }
  tB[(long)bv * 512 + h * 64 + e0]     = a0 * 0.125f;
  tB[(long)bv * 512 + h * 64 + e0 + 1] = a1 * 0.125f;
}

// ---------------------------------------------------------------------------
// K1 (anchor only): [64 x 512] = [64 x 256] @ [256 x 512] bf16 MFMA GEMM
// + bias + LN.  mode 1: block = 64 b's for one v; out ha fp32 [b][v][512].
// ---------------------------------------------------------------------------
union K1Smem {
  struct { u16 A[64 * 256]; u16 B[16384]; } p;   // 32 KB + 32 KB
  u16 S[64 * 512];                               // 64 KB (epilogue)
};

__global__ __launch_bounds__(512, 4) void k1_gemm_ln(
    const float* __restrict__ X,
    const u16*   __restrict__ Wt,
    const float* __restrict__ bias,
    const float* __restrict__ gamma,
    const float* __restrict__ betap,
    u16*   __restrict__ hn,
    float* __restrict__ ha,
    int mode, int b0, int Bc)
{
  __shared__ K1Smem sm;
  const int v = blockIdx.y, blk = blockIdx.x, t = threadIdx.x;
  const int w = t >> 6, l = t & 63, lm = l & 15, lg = l >> 4;
  const int wm = w & 1, wn = w >> 1;

  float bcol[8];
  #pragma unroll
  for (int tn = 0; tn < 8; ++tn) bcol[tn] = bias[v * 512 + wn * 128 + tn * 16 + lm];

  {
    int row = t >> 3;
    int cbase = (t & 7) * 32;
    long grow;
    if (mode == 0) { int b = b0 + blk * 2 + (row >> 5); grow = ((long)(b * 3 + v) * 32 + (row & 31)) * 256; }
    else           { int b = blk * 64 + row;            grow = (long)(b * 3 + v) * 256; }
    const float4* src = (const float4*)(X + grow + cbase);
    int sw = row & 7;
    #pragma unroll
    for (int j = 0; j < 8; ++j) {
      float4 f = src[j];
      int col = cbase + j * 4;
      int c = col >> 3, m = col & 7;
      ushort4 u;
      u.x = f2bf(f.x); u.y = f2bf(f.y); u.z = f2bf(f.z); u.w = f2bf(f.w);
      *(ushort4*)&sm.p.A[row * 256 + ((c ^ sw) << 3) + m] = u;
    }
  }

  f4 acc[2][8];
  #pragma unroll
  for (int i = 0; i < 2; ++i)
    #pragma unroll
    for (int j = 0; j < 8; ++j) { f4 z = {0.f, 0.f, 0.f, 0.f}; acc[i][j] = z; }

  const u16* Wbase = Wt + (long)v * 8 * 16384;
  for (int kt = 0; kt < 8; ++kt) {
    __syncthreads();
    {
      const u16* gp = Wbase + (long)kt * 16384 + t * 8;
      u16* lp = &sm.p.B[t * 8];
      #pragma unroll
      for (int r = 0; r < 4; ++r) gl2lds16(gp + r * 4096, lp + r * 4096);
    }
    __syncthreads();
    bf8 af[2];
    #pragma unroll
    for (int tm = 0; tm < 2; ++tm) {
      int row = wm * 32 + tm * 16 + lm;
      int c = kt * 4 + lg;
      af[tm] = *(const bf8*)&sm.p.A[row * 256 + ((c ^ (row & 7)) << 3)];
    }
    #pragma unroll
    for (int tn = 0; tn < 8; ++tn) {
      int n = wn * 128 + tn * 16 + lm;
      bf8 bv = *(const bf8*)&sm.p.B[n * 32 + ((lg ^ ((n >> 1) & 3)) << 3)];
      acc[0][tn] = __builtin_amdgcn_mfma_f32_16x16x32_bf16(af[0], bv, acc[0][tn], 0, 0, 0);
      acc[1][tn] = __builtin_amdgcn_mfma_f32_16x16x32_bf16(af[1], bv, acc[1][tn], 0, 0, 0);
    }
  }
  __syncthreads();

  #pragma unroll
  for (int tm = 0; tm < 2; ++tm)
    #pragma unroll
    for (int tn = 0; tn < 8; ++tn) {
      int col = wn * 128 + tn * 16 + lm;
      int c = col >> 3, m = col & 7;
      #pragma unroll
      for (int r = 0; r < 4; ++r) {
        int row = wm * 32 + tm * 16 + lg * 4 + r;
        sm.S[row * 512 + ((c ^ (row & 7)) << 3) + m] = f2bf(acc[tm][tn][r] + bcol[tn]);
      }
    }
  __syncthreads();

  {
    int row = t >> 3, ch = t & 7, sw = row & 7;
    float s1 = 0.f, s2 = 0.f;
    #pragma unroll
    for (int j = 0; j < 8; ++j) {
      int c = j * 8 + ch;
      uint4 q = *(const uint4*)&sm.S[row * 512 + ((c ^ sw) << 3)];
      float x0 = bflo(q.x), x1 = bfhi(q.x), x2 = bflo(q.y), x3 = bfhi(q.y);
      float x4 = bflo(q.z), x5 = bfhi(q.z), x6 = bflo(q.w), x7 = bfhi(q.w);
      s1 += ((x0 + x1) + (x2 + x3)) + ((x4 + x5) + (x6 + x7));
      s2 += ((x0*x0 + x1*x1) + (x2*x2 + x3*x3)) + ((x4*x4 + x5*x5) + (x6*x6 + x7*x7));
    }
    #pragma unroll
    for (int d = 1; d < 8; d <<= 1) { s1 += __shfl_xor(s1, d, 64); s2 += __shfl_xor(s2, d, 64); }
    float mu = s1 * (1.f / 512.f);
    float var = s2 * (1.f / 512.f) - mu * mu;
    float rs = rsqrtf(var + 1e-5f);
    #pragma unroll
    for (int j = 0; j < 8; ++j) {
      int c = j * 8 + ch;
      uint4 q = *(const uint4*)&sm.S[row * 512 + ((c ^ sw) << 3)];
      int col0 = c * 8;
      float4 g0 = *(const float4*)&gamma[v * 512 + col0];
      float4 g1 = *(const float4*)&gamma[v * 512 + col0 + 4];
      float4 e0 = *(const float4*)&betap[v * 512 + col0];
      float4 e1 = *(const float4*)&betap[v * 512 + col0 + 4];
      float y0 = (bflo(q.x) - mu) * rs * g0.x + e0.x;
      float y1 = (bfhi(q.x) - mu) * rs * g0.y + e0.y;
      float y2 = (bflo(q.y) - mu) * rs * g0.z + e0.z;
      float y3 = (bfhi(q.y) - mu) * rs * g0.w + e0.w;
      float y4 = (bflo(q.z) - mu) * rs * g1.x + e1.x;
      float y5 = (bfhi(q.z) - mu) * rs * g1.y + e1.y;
      float y6 = (bflo(q.w) - mu) * rs * g1.z + e1.z;
      float y7 = (bfhi(q.w) - mu) * rs * g1.w + e1.w;
      if (mode == 0) {
        uint4 q4;
        q4.x = (u32)f2bf(y0) | ((u32)f2bf(y1) << 16);
        q4.y = (u32)f2bf(y2) | ((u32)f2bf(y3) << 16);
        q4.z = (u32)f2bf(y4) | ((u32)f2bf(y5) << 16);
        q4.w = (u32)f2bf(y6) | ((u32)f2bf(y7) << 16);
        int bl_ = blk * 2 + (row >> 5), krow = row & 31;
        u16* dst = hn + (((long)(v * 8 + j) * Bc + bl_) * 32 + krow) * 64 + ch * 8;
        *(uint4*)dst = q4;
      } else {
        int b = blk * 64 + row;
        float* dst = ha + (long)(b * 3 + v) * 512 + col0;
        float4 w0, w1;
        w0.x = y0; w0.y = y1; w0.z = y2; w0.w = y3;
        w1.x = y4; w1.y = y5; w1.z = y6; w1.w = y7;
        *(float4*)dst = w0;
        *(float4*)(dst + 4) = w1;
      }
    }
  }
}

// ---------------------------------------------------------------------------
// K12 v2: FUSED neighbor encoder + per-view attention, spill-free.
// Changes vs v1: tS = ha@Wqk GEMV hoisted to k_tq (staged from global here);
// V-proj pair loop unroll(1); Wo GEMV partial unroll.  Register peak is the
// GEMM phase's 64 VGPR + 64 AGPR = 128 = the (512,4) cap.
// ---------------------------------------------------------------------------
__global__ __launch_bounds__(512, 4) void k12_fused(
    const float* __restrict__ X,      // x_neighbors
    const u16*   __restrict__ Wt,     // nWt (swizzled LDS-image tiles)
    const float* __restrict__ bias,   // nb
    const float* __restrict__ gamma,  // ng
    const float* __restrict__ betap,  // nbeta
    const float* __restrict__ ha,     // [B][V][512] f32
    const u16*   __restrict__ Wvt,    // [V][H][64][64] bf16 transposed
    const float* __restrict__ tB,     // [B][V][H][64] f32 = ha@Wqk * 0.125
    const float* __restrict__ Wo,     // [V][H][64][64] f32
    const float* __restrict__ ew,     // [B][V][K]
    const float* __restrict__ gls,    // [V][H]
    float* __restrict__ vt)           // [B][H][V][64]
{
  __shared__ K1Smem sm;
  __shared__ float tS[1024];     // [2b][8h][64e]
  __shared__ float aS[512];      // [2b][8h][32k]
  __shared__ float oS[1024];     // [2b][8h][64d]
  __shared__ float haS[1024];    // [2b][512]

  const int v = blockIdx.y, blk = blockIdx.x, t = threadIdx.x;
  const int w = t >> 6, l = t & 63, lm = l & 15, lg = l >> 4;
  const int wm = w & 1, wn = w >> 1;

  float bcol[8];
  #pragma unroll
  for (int tn = 0; tn < 8; ++tn) bcol[tn] = bias[v * 512 + wn * 128 + tn * 16 + lm];

  // ---- stage A once (fp32 -> bf16, XOR-swizzled rows): 2 b's x 32 k ----
  {
    int row = t >> 3;
    int cbase = (t & 7) * 32;
    int b = blk * 2 + (row >> 5);
    long grow = ((long)(b * 3 + v) * 32 + (row & 31)) * 256;
    const float4* src = (const float4*)(X + grow + cbase);
    int sw = row & 7;
    #pragma unroll
    for (int j = 0; j < 8; ++j) {
      float4 f = src[j];
      int col = cbase + j * 4;
      int c = col >> 3, m = col & 7;
      ushort4 u;
      u.x = f2bf(f.x); u.y = f2bf(f.y); u.z = f2bf(f.z); u.w = f2bf(f.w);
      *(ushort4*)&sm.p.A[row * 256 + ((c ^ sw) << 3) + m] = u;
    }
  }
  // ---- stage ha slice (residual) and precomputed tB for both b's ----
  {
    int b = t >> 8, e = (t & 255) * 2;
    *(float2*)&haS[b * 512 + e] =
        *(const float2*)&ha[((long)(blk * 2 + b) * 3 + v) * 512 + e];
    *(float2*)&tS[b * 512 + e] =
        *(const float2*)&tB[((long)(blk * 2 + b) * 3 + v) * 512 + e];
  }

  f4 acc[2][8];
  #pragma unroll
  for (int i = 0; i < 2; ++i)
    #pragma unroll
    for (int j = 0; j < 8; ++j) { f4 z = {0.f, 0.f, 0.f, 0.f}; acc[i][j] = z; }

  // ---- K loop: 2 barriers/kt, B via async DMA ----
  const u16* Wbase = Wt + (long)v * 8 * 16384;
  for (int kt = 0; kt < 8; ++kt) {
    __syncthreads();
    {
      const u16* gp = Wbase + (long)kt * 16384 + t * 8;
      u16* lp = &sm.p.B[t * 8];
      #pragma unroll
      for (int r = 0; r < 4; ++r) gl2lds16(gp + r * 4096, lp + r * 4096);
    }
    __syncthreads();
    bf8 af[2];
    #pragma unroll
    for (int tm = 0; tm < 2; ++tm) {
      int row = wm * 32 + tm * 16 + lm;
      int c = kt * 4 + lg;
      af[tm] = *(const bf8*)&sm.p.A[row * 256 + ((c ^ (row & 7)) << 3)];
    }
    #pragma unroll
    for (int tn = 0; tn < 8; ++tn) {
      int n = wn * 128 + tn * 16 + lm;
      bf8 bv = *(const bf8*)&sm.p.B[n * 32 + ((lg ^ ((n >> 1) & 3)) << 3)];
      acc[0][tn] = __builtin_amdgcn_mfma_f32_16x16x32_bf16(af[0], bv, acc[0][tn], 0, 0, 0);
      acc[1][tn] = __builtin_amdgcn_mfma_f32_16x16x32_bf16(af[1], bv, acc[1][tn], 0, 0, 0);
    }
  }
  __syncthreads();

  // ---- dump z = acc + bias into S (64x512 bf16, XOR-swizzled) ----
  #pragma unroll
  for (int tm = 0; tm < 2; ++tm)
    #pragma unroll
    for (int tn = 0; tn < 8; ++tn) {
      int col = wn * 128 + tn * 16 + lm;
      int c = col >> 3, m = col & 7;
      #pragma unroll
      for (int r = 0; r < 4; ++r) {
        int row = wm * 32 + tm * 16 + lg * 4 + r;
        sm.S[row * 512 + ((c ^ (row & 7)) << 3) + m] = f2bf(acc[tm][tn][r] + bcol[tn]);
      }
    }
  __syncthreads();

  // ---- LayerNorm in place (8 threads/row) ----
  {
    int row = t >> 3, ch = t & 7, sw = row & 7;
    float s1 = 0.f, s2 = 0.f;
    #pragma unroll
    for (int j = 0; j < 8; ++j) {
      int c = j * 8 + ch;
      uint4 q = *(const uint4*)&sm.S[row * 512 + ((c ^ sw) << 3)];
      float x0 = bflo(q.x), x1 = bfhi(q.x), x2 = bflo(q.y), x3 = bfhi(q.y);
      float x4 = bflo(q.z), x5 = bfhi(q.z), x6 = bflo(q.w), x7 = bfhi(q.w);
      s1 += ((x0 + x1) + (x2 + x3)) + ((x4 + x5) + (x6 + x7));
      s2 += ((x0*x0 + x1*x1) + (x2*x2 + x3*x3)) + ((x4*x4 + x5*x5) + (x6*x6 + x7*x7));
    }
    #pragma unroll
    for (int d = 1; d < 8; d <<= 1) { s1 += __shfl_xor(s1, d, 64); s2 += __shfl_xor(s2, d, 64); }
    float mu = s1 * (1.f / 512.f);
    float var = s2 * (1.f / 512.f) - mu * mu;
    float rs = rsqrtf(var + 1e-5f);
    #pragma unroll
    for (int j = 0; j < 8; ++j) {
      int c = j * 8 + ch;
      u16* sp = &sm.S[row * 512 + ((c ^ sw) << 3)];
      uint4 q = *(const uint4*)sp;
      int col0 = c * 8;
      float4 g0 = *(const float4*)&gamma[v * 512 + col0];
      float4 g1 = *(const float4*)&gamma[v * 512 + col0 + 4];
      float4 e0 = *(const float4*)&betap[v * 512 + col0];
      float4 e1 = *(const float4*)&betap[v * 512 + col0 + 4];
      float y0 = (bflo(q.x) - mu) * rs * g0.x + e0.x;
      float y1 = (bfhi(q.x) - mu) * rs * g0.y + e0.y;
      float y2 = (bflo(q.y) - mu) * rs * g0.z + e0.z;
      float y3 = (bfhi(q.y) - mu) * rs * g0.w + e0.w;
      float y4 = (bflo(q.z) - mu) * rs * g1.x + e1.x;
      float y5 = (bfhi(q.z) - mu) * rs * g1.y + e1.y;
      float y6 = (bflo(q.w) - mu) * rs * g1.z + e1.z;
      float y7 = (bfhi(q.w) - mu) * rs * g1.w + e1.w;
      uint4 q4;
      q4.x = (u32)f2bf(y0) | ((u32)f2bf(y1) << 16);
      q4.y = (u32)f2bf(y2) | ((u32)f2bf(y3) << 16);
      q4.z = (u32)f2bf(y4) | ((u32)f2bf(y5) << 16);
      q4.w = (u32)f2bf(y6) | ((u32)f2bf(y7) << 16);
      *(uint4*)sp = q4;                     // hn, bit-identical to old path
    }
  }
  __syncthreads();

  // ---- scores + softmax: thread = (b,h,k), 2*8*32 = 512 ----
  {
    int b = t >> 8, h = (t >> 5) & 7, k = t & 31;
    float x = gls[v * 8 + h];
    float gsc = (x > 20.f) ? x : log1pf(expf(x));
    int r = b * 32 + k, sw = r & 7;
    const float* tb = &tS[(b * 8 + h) * 64];
    float s = 0.f;
    #pragma unroll
    for (int j = 0; j < 8; ++j) {
      int c8 = h * 8 + j;
      uint4 q = *(const uint4*)&sm.S[r * 512 + ((c8 ^ sw) << 3)];
      const float* tj = tb + j * 8;
      s += tj[0] * bflo(q.x) + tj[1] * bfhi(q.x)
         + tj[2] * bflo(q.y) + tj[3] * bfhi(q.y)
         + tj[4] * bflo(q.z) + tj[5] * bfhi(q.z)
         + tj[6] * bflo(q.w) + tj[7] * bfhi(q.w);
    }
    float e_w = ew[((long)(blk * 2 + b) * 3 + v) * 32 + k];
    s += gsc * logf(e_w + 1e-6f);
    float m = s;
    #pragma unroll
    for (int d = 1; d < 32; d <<= 1) m = fmaxf(m, __shfl_xor(m, d, 64));
    float exs = expf(s - m), sum = exs;
    #pragma unroll
    for (int d = 1; d < 32; d <<= 1) sum += __shfl_xor(sum, d, 64);
    aS[(b * 8 + h) * 32 + k] = exs / sum;
  }
  __syncthreads();

  // ---- per wave: 2 (b,h) pairs: V-proj MFMA from S + o = attn@V ----
  // unroll(1): only one aV[2][4] (32 AGPR) live at a time.
  #pragma unroll 1
  for (int i = 0; i < 2; ++i) {
    int p = w * 2 + i, b = p >> 3, h = p & 7;
    const u16* wvg = Wvt + (long)(v * 8 + h) * 4096;
    f4 aV[2][4];
    #pragma unroll
    for (int a = 0; a < 2; ++a)
      #pragma unroll
      for (int j = 0; j < 4; ++j) { f4 z = {0.f, 0.f, 0.f, 0.f}; aV[a][j] = z; }
    #pragma unroll
    for (int ks = 0; ks < 2; ++ks) {
      int ko = ks * 32 + lg * 8;
      bf8 af[2];
      #pragma unroll
      for (int tm = 0; tm < 2; ++tm) {
        int r = b * 32 + tm * 16 + lm;
        int c8 = h * 8 + ks * 4 + lg;
        af[tm] = *(const bf8*)&sm.S[r * 512 + ((c8 ^ (r & 7)) << 3)];
      }
      #pragma unroll
      for (int tn = 0; tn < 4; ++tn) {
        bf8 bv = *(const bf8*)&wvg[(tn * 16 + lm) * 64 + ko];
        #pragma unroll
        for (int tm = 0; tm < 2; ++tm)
          aV[tm][tn] = __builtin_amdgcn_mfma_f32_16x16x32_bf16(af[tm], bv, aV[tm][tn], 0, 0, 0);
      }
    }
    float pp[4] = {0.f, 0.f, 0.f, 0.f};
    #pragma unroll
    for (int tm = 0; tm < 2; ++tm)
      #pragma unroll
      for (int r4 = 0; r4 < 4; ++r4) {
        int k = tm * 16 + lg * 4 + r4;
        float a = aS[p * 32 + k];
        #pragma unroll
        for (int tn = 0; tn < 4; ++tn) pp[tn] += a * aV[tm][tn][r4];
      }
    #pragma unroll
    for (int tn = 0; tn < 4; ++tn) {
      float x = pp[tn];
      x += __shfl_xor(x, 16, 64);
      x += __shfl_xor(x, 32, 64);
      if (l < 16) oS[p * 64 + tn * 16 + lm] = x;
    }
  }
  __syncthreads();

  // ---- out = o @ Wo + ha (residual); thread = (h,e), loop over b ----
  {
    int h = t >> 6, e = t & 63;
    const float* wo = Wo + (long)(v * 8 + h) * 4096;
    float a0 = haS[h * 64 + e];
    float a1 = haS[512 + h * 64 + e];
    const float* o0 = &oS[h * 64];
    const float* o1 = &oS[512 + h * 64];
    #pragma unroll 4
    for (int d = 0; d < 64; ++d) {
      float wv = wo[d * 64 + e];
      a0 += o0[d] * wv;
      a1 += o1[d] * wv;
    }
    vt[(((long)(blk * 2 + 0) * 8 + h) * 3 + v) * 64 + e] = a0;
    vt[(((long)(blk * 2 + 1) * 8 + h) * 3 + v) * 64 + e] = a1;
  }
}

// ---------------------------------------------------------------------------
// K3: router MLP (fp32). Block = 4 b's (512 blocks -> full GPU).
// ---------------------------------------------------------------------------
__global__ __launch_bounds__(256) void k3_router(
    const float* __restrict__ g, const float* __restrict__ rW1, const float* __restrict__ rb1,
    const float* __restrict__ rW2, const float* __restrict__ rb2,
    const float* __restrict__ vW, const float* __restrict__ vb,
    const float* __restrict__ mW, const float* __restrict__ mb,
    const float* __restrict__ gW, const float* __restrict__ gb,
    float* __restrict__ pi, float* __restrict__ beta_o, float* __restrict__ gate_o)
{
  __shared__ float gs[4 * 128], h1[4 * 256], h2[4 * 256], lgt[4 * 40];
  int t = threadIdx.x, bb = blockIdx.x * 4;
  #pragma unroll
  for (int r = 0; r < 2; ++r) { int idx = r * 256 + t; gs[idx] = g[(long)bb * 128 + idx]; }
  __syncthreads();
  {
    int bl = t >> 6, e0 = (t & 63) * 4;
    float acc[4];
    #pragma unroll
    for (int j = 0; j < 4; ++j) acc[j] = rb1[e0 + j];
    for (int i = 0; i < 128; ++i) {
      float gv = gs[bl * 128 + i];
      const float* wr = rW1 + i * 256 + e0;
      #pragma unroll
      for (int j = 0; j < 4; ++j) acc[j] += gv * wr[j];
    }
    #pragma unroll
    for (int j = 0; j < 4; ++j) { float x = acc[j]; h1[bl * 256 + e0 + j] = 0.5f * x * (1.f + erff(x * 0.70710678118f)); }
  }
  __syncthreads();
  {
    int bl = t >> 6, e0 = (t & 63) * 4;
    float acc[4];
    #pragma unroll
    for (int j = 0; j < 4; ++j) acc[j] = rb2[e0 + j];
    for (int i = 0; i < 256; ++i) {
      float hv = h1[bl * 256 + i];
      const float* wr = rW2 + i * 256 + e0;
      #pragma unroll
      for (int j = 0; j < 4; ++j) acc[j] += hv * wr[j];
    }
    #pragma unroll
    for (int j = 0; j < 4; ++j) { float x = acc[j]; h2[bl * 256 + e0 + j] = 0.5f * x * (1.f + erff(x * 0.70710678118f)); }
  }
  __syncthreads();
  if (t < 160) {
    int bl = t / 40, j = t % 40;
    const float* W; float bs; int col, stride;
    if (j < 24)      { W = vW; col = j;      stride = 24; bs = vb[j]; }
    else if (j < 32) { W = mW; col = j - 24; stride = 8;  bs = mb[j - 24]; }
    else             { W = gW; col = j - 32; stride = 8;  bs = gb[j - 32]; }
    float acc = bs;
    for (int i = 0; i < 256; ++i) acc += h2[bl * 256 + i] * W[i * stride + col];
    lgt[bl * 40 + j] = acc;
  }
  __syncthreads();
  if (t < 4) {
    int b = bb + t;
    const float* L = &lgt[t * 40];
    #pragma unroll
    for (int hh = 0; hh < 8; ++hh) {
      float a0 = L[hh * 3], a1 = L[hh * 3 + 1], a2v = L[hh * 3 + 2];
      float m = fmaxf(a0, fmaxf(a1, a2v));
      float x0 = expf(a0 - m), x1 = expf(a1 - m), x2 = expf(a2v - m);
      float inv = 1.f / (x0 + x1 + x2);
      pi[b * 24 + hh * 3 + 0] = x0 * inv;
      pi[b * 24 + hh * 3 + 1] = x1 * inv;
      pi[b * 24 + hh * 3 + 2] = x2 * inv;
      beta_o[b * 8 + hh] = 1.f / (1.f + expf(-L[24 + hh]));
    }
    float m = L[32];
    #pragma unroll
    for (int hh = 1; hh < 8; ++hh) m = fmaxf(m, L[32 + hh]);
    float s = 0.f, ex[8];
    #pragma unroll
    for (int hh = 0; hh < 8; ++hh) { ex[hh] = expf(L[32 + hh] - m); s += ex[hh]; }
    float inv = 1.f / s;
    #pragma unroll
    for (int hh = 0; hh < 8; ++hh) gate_o[b * 8 + hh] = ex[hh] * inv;
  }
}

// ---------------------------------------------------------------------------
// K4: pi-mixture + cross-view attention + output. Block = 4 b's, fp32.
// ---------------------------------------------------------------------------
__global__ __launch_bounds__(256) void k4_cross(
    const float* __restrict__ vtg, const float* __restrict__ pig,
    const float* __restrict__ betag, const float* __restrict__ gateg,
    const float* __restrict__ cWq, const float* __restrict__ cWk,
    const float* __restrict__ cWv, const float* __restrict__ cWo,
    float* __restrict__ out)
{
  __shared__ float smem[12544];
  float* vts   = smem;          // 6144: [4][8][3][64]
  float* mixs  = smem + 6144;   // 2048
  float* buf1  = smem + 8192;   // 2048: qc, then y
  float* buf2  = smem + 10240;  // 2048: w,  then cr
  float* a2s   = smem + 12288;  // 96
  float* pis   = smem + 12384;  // 96
  float* betas = smem + 12480;  // 32
  float* gates = smem + 12512;  // 32

  int t = threadIdx.x, bblk = blockIdx.x * 4;
  {
    const float4* src = (const float4*)(vtg + (long)bblk * 1536);
    #pragma unroll
    for (int r = 0; r < 6; ++r) ((float4*)vts)[r * 256 + t] = src[r * 256 + t];
    if (t < 96) pis[t] = pig[bblk * 24 + t];
    if (t < 32) { betas[t] = betag[bblk * 8 + t]; gates[t] = gateg[bblk * 8 + t]; }
  }
  __syncthreads();
  int bl = t >> 6, hh = (t >> 3) & 7, e0 = (t & 7) * 8;
  const float* vbh = &vts[(bl * 8 + hh) * 192];
  {
    float p0 = pis[bl * 24 + hh * 3], p1 = pis[bl * 24 + hh * 3 + 1], p2 = pis[bl * 24 + hh * 3 + 2];
    #pragma unroll
    for (int j = 0; j < 8; ++j) {
      int e = e0 + j;
      mixs[(bl * 8 + hh) * 64 + e] = p0 * vbh[e] + p1 * vbh[64 + e] + p2 * vbh[128 + e];
    }
  }
  __syncthreads();
  {
    float acc[8] = {0.f,0.f,0.f,0.f,0.f,0.f,0.f,0.f};
    const float* M = &mixs[(bl * 8 + hh) * 64];
    for (int d = 0; d < 64; ++d) {
      float mv = M[d];
      const float* wr = &cWq[(hh * 64 + d) * 64 + e0];
      #pragma unroll
      for (int j = 0; j < 8; ++j) acc[j] += mv * wr[j];
    }
    #pragma unroll
    for (int j = 0; j < 8; ++j) buf1[(bl * 8 + hh) * 64 + e0 + j] = acc[j] * 0.125f;
  }
  __syncthreads();
  {
    const float* Q = &buf1[(bl * 8 + hh) * 64];
    #pragma unroll
    for (int d2 = 0; d2 < 8; ++d2) {
      const float* wr = &cWk[(hh * 64 + e0 + d2) * 64];
      float a = 0.f;
      for (int e = 0; e < 64; ++e) a += wr[e] * Q[e];
      buf2[(bl * 8 + hh) * 64 + e0 + d2] = a;
    }
  }
  __syncthreads();
  if (t < 32) {
    int b2 = t >> 3, h2 = t & 7;
    const float* Wd = &buf2[(b2 * 8 + h2) * 64];
    const float* vb2 = &vts[(b2 * 8 + h2) * 192];
    float s[3];
    #pragma unroll
    for (int v3 = 0; v3 < 3; ++v3) {
      float a = 0.f;
      for (int d = 0; d < 64; ++d) a += Wd[d] * vb2[v3 * 64 + d];
      s[v3] = a + logf(pis[b2 * 24 + h2 * 3 + v3] + 1e-6f);
    }
    float m = fmaxf(s[0], fmaxf(s[1], s[2]));
    float x0 = expf(s[0] - m), x1 = expf(s[1] - m), x2 = expf(s[2] - m);
    float inv = 1.f / (x0 + x1 + x2);
    a2s[(b2 * 8 + h2) * 3 + 0] = x0 * inv;
    a2s[(b2 * 8 + h2) * 3 + 1] = x1 * inv;
    a2s[(b2 * 8 + h2) * 3 + 2] = x2 * inv;
  }
  __syncthreads();
  {
    float a0 = a2s[(bl * 8 + hh) * 3], a1 = a2s[(bl * 8 + hh) * 3 + 1], a2v = a2s[(bl * 8 + hh) * 3 + 2];
    #pragma unroll
    for (int j = 0; j < 8; ++j) {
      int e = e0 + j;
      buf1[(bl * 8 + hh) * 64 + e] = a0 * vbh[e] + a1 * vbh[64 + e] + a2v * vbh[128 + e];
    }
  }
  __syncthreads();
  {
    float acc[8] = {0.f,0.f,0.f,0.f,0.f,0.f,0.f,0.f};
    const float* Y = &buf1[(bl * 8 + hh) * 64];
    for (int d = 0; d < 64; ++d) {
      float yv = Y[d];
      const float* wr = &cWv[(hh * 64 + d) * 64 + e0];
      #pragma unroll
      for (int j = 0; j < 8; ++j) acc[j] += yv * wr[j];
    }
    #pragma unroll
    for (int j = 0; j < 8; ++j) buf2[(bl * 8 + hh) * 64 + e0 + j] = acc[j];
  }
  __syncthreads();
  {
    float acc[8] = {0.f,0.f,0.f,0.f,0.f,0.f,0.f,0.f};
    const float* C2 = &buf2[(bl * 8 + hh) * 64];
    for (int d = 0; d < 64; ++d) {
      float cv = C2[d];
      const float* wr = &cWo[(hh * 64 + d) * 64 + e0];
      #pragma unroll
      for (int j = 0; j < 8; ++j) acc[j] += cv * wr[j];
    }
    float bt = betas[bl * 8 + hh], gt = gates[bl * 8 + hh];
    const float* M = &mixs[(bl * 8 + hh) * 64];
    #pragma unroll
    for (int j = 0; j < 8; ++j)
      out[((long)(bblk + bl) * 8 + hh) * 64 + e0 + j] = gt * (bt * acc[j] + (1.f - bt) * M[e0 + j]);
  }
}

// ---------------------------------------------------------------------------
extern "C" void kernel_launch(void* const* d_in, const int* in_sizes, int n_in,
                              void* d_out, int out_size, void* d_ws, size_t ws_size,
                              hipStream_t stream) {
  const float* x_anchor    = (const float*)d_in[0];
  const float* x_neighbors = (const float*)d_in[1];
  const float* edge_w      = (const float*)d_in[2];
  const float* g           = (const float*)d_in[3];
  const float* aW  = (const float*)d_in[4];
  const float* ab  = (const float*)d_in[5];
  const float* ag  = (const float*)d_in[6];
  const float* abeta = (const float*)d_in[7];
  const float* nW  = (const float*)d_in[8];
  const float* nb  = (const float*)d_in[9];
  const float* ng  = (const float*)d_in[10];
  const float* nbeta = (const float*)d_in[11];
  const float* Wq  = (const float*)d_in[12];
  const float* Wk  = (const float*)d_in[13];
  const float* Wv  = (const float*)d_in[14];
  const float* Wo  = (const float*)d_in[15];
  const float* gls = (const float*)d_in[16];
  const float* cWq = (const float*)d_in[17];
  const float* cWk = (const float*)d_in[18];
  const float* cWv = (const float*)d_in[19];
  const float* cWo = (const float*)d_in[20];
  const float* rW1 = (const float*)d_in[21];
  const float* rb1 = (const float*)d_in[22];
  const float* rW2 = (const float*)d_in[23];
  const float* rb2 = (const float*)d_in[24];
  const float* vW  = (const float*)d_in[25];
  const float* vb  = (const float*)d_in[26];
  const float* mW  = (const float*)d_in[27];
  const float* mb  = (const float*)d_in[28];
  const float* gW  = (const float*)d_in[29];
  const float* gb  = (const float*)d_in[30];

  // workspace carve-up
  char* p = (char*)d_ws;
  u16* nWt = (u16*)p;  p += 786432;
  u16* aWt = (u16*)p;  p += 786432;
  u16* Wvt = (u16*)p;  p += 196608;
  float* WqkB = (float*)p; p += 393216;
  float* ha   = (float*)p; p += 12582912;
  float* vtb  = (float*)p; p += 12582912;
  float* tqB  = (float*)p; p += 12582912;
  float* pib  = (float*)p; p += 196608;
  float* betb = (float*)p; p += 65536;
  float* gatb = (float*)p; p += 65536;
  (void)ws_size;

  k0_prep<<<1920, 256, 0, stream>>>(nW, aW, Wv, nWt, aWt, Wvt);
  k0_wqk<<<24, 256, 0, stream>>>(Wq, Wk, WqkB);
  // anchor encoder: ha (fp32)
  k1_gemm_ln<<<dim3(32, 3), 512, 0, stream>>>(x_anchor, aWt, ab, ag, abeta,
                                              (u16*)nullptr, ha, 1, 0, 2048);
  // tB = (ha @ Wqk) * 0.125, hoisted out of the fused kernel
  k_tq<<<6144, 256, 0, stream>>>(ha, WqkB, tqB);
  k3_router<<<512, 256, 0, stream>>>(g, rW1, rb1, rW2, rb2, vW, vb, mW, mb, gW, gb,
                                     pib, betb, gatb);
  // fused neighbor encoder + per-view attention (single pass over B)
  k12_fused<<<dim3(1024, 3), 512, 0, stream>>>(x_neighbors, nWt, nb, ng, nbeta,
                                               ha, Wvt, tqB, Wo, edge_w, gls, vtb);
  k4_cross<<<512, 256, 0, stream>>>(vtb, pib, betb, gatb, cWq, cWk, cWv, cWo,
                                    (float*)d_out);
}

// Round 3
// 732.164 us; speedup vs baseline: 1.1142x; 1.0475x over previous
//
#include <hip/hip_runtime.h>

// Problem constants
#define B_   2048
#define V_   3
#define K_   32
#define DIN_ 256
#define H_   8
#define DH_  64
#define REP_ 512

typedef unsigned short u16;
typedef unsigned int   u32;
typedef __bf16 bf8 __attribute__((ext_vector_type(8)));
typedef float  f4  __attribute__((ext_vector_type(4)));

static __device__ __forceinline__ u16 f2bf(float f) {
  union { float f; u32 i; } x; x.f = f;
  u32 r = (x.i + 0x7FFFu + ((x.i >> 16) & 1u)) >> 16;   // RNE
  return (u16)r;
}
static __device__ __forceinline__ float bf2f(u16 u) {
  union { u32 i; float f; } x; x.i = ((u32)u) << 16;
  return x.f;
}
static __device__ __forceinline__ float bflo(u32 q) {
  union { u32 i; float f; } x; x.i = q << 16; return x.f;
}
static __device__ __forceinline__ float bfhi(u32 q) {
  union { u32 i; float f; } x; x.i = q & 0xffff0000u; return x.f;
}

// async global->LDS DMA, 16 B per lane; lane i lands at base + i*16
static __device__ __forceinline__ void gl2lds16(const u16* g, u16* l) {
  __builtin_amdgcn_global_load_lds(
      (const __attribute__((address_space(1))) unsigned int*)(g),
      (__attribute__((address_space(3))) unsigned int*)(l), 16, 0, 0);
}

// ---------------------------------------------------------------------------
// K0: weight prep.
//  nWt/aWt: [v][kt(8)] x 32KB "LDS image": element at hw index
//    n*32 + (c ^ ((n>>1)&3))*8 + m   equals  W[k = kt*32 + c*8 + m][n]  (bf16)
//  Wvt: [v][h][e(64)][d(64)] bf16 (transposed: B-operand layout)
// ---------------------------------------------------------------------------
__global__ __launch_bounds__(256) void k0_prep(
    const float* __restrict__ nW, const float* __restrict__ aW,
    const float* __restrict__ Wv,
    u16* __restrict__ nWt, u16* __restrict__ aWt,
    u16* __restrict__ Wvt)
{
  int id = blockIdx.x * 256 + threadIdx.x;
  if (id < 393216) {                       // 3*8*512*32
    int v  = id / 131072, r  = id % 131072;
    int kt = r / 16384,   r2 = r % 16384;
    int n  = r2 >> 5;
    int s  = (r2 >> 3) & 3;
    int m  = r2 & 7;
    int c  = s ^ ((n >> 1) & 3);
    int k  = kt * 32 + c * 8 + m;
    int src = (v * 256 + k) * 512 + n;
    nWt[id] = f2bf(nW[src]);
    aWt[id] = f2bf(aW[src]);
  } else {
    int j = id - 393216;                   // < 98304 = 3*8*64*64
    int vh = j / 4096, r = j % 4096;
    int e = r / 64, d = r % 64;
    int src = (vh * 64 + d) * 64 + e;
    Wvt[j] = f2bf(Wv[src]);
  }
}

// ---------------------------------------------------------------------------
// K0b: Wqk[vh][d][e] = sum_c Wq[vh][d][c] * Wk[vh][e][c]   (fp32)
// ---------------------------------------------------------------------------
__global__ __launch_bounds__(256) void k0_wqk(
    const float* __restrict__ Wq, const float* __restrict__ Wk,
    float* __restrict__ Wqk)
{
  int vh = blockIdx.x, t = threadIdx.x;
  __shared__ float wq[4096], wkT[4096];
  #pragma unroll
  for (int i = 0; i < 16; ++i) {
    int idx = i * 256 + t;
    wq[idx] = Wq[(long)vh * 4096 + idx];
    int e = idx >> 6, c = idx & 63;
    wkT[c * 64 + e] = Wk[(long)vh * 4096 + e * 64 + c];
  }
  __syncthreads();
  int d = t >> 2, e0 = (t & 3) * 16;
  float acc[16];
  #pragma unroll
  for (int j = 0; j < 16; ++j) acc[j] = 0.f;
  for (int c = 0; c < 64; ++c) {
    float a = wq[d * 64 + c];
    const float* wr = &wkT[c * 64 + e0];
    #pragma unroll
    for (int j = 0; j < 16; ++j) acc[j] += a * wr[j];
  }
  #pragma unroll
  for (int j = 0; j < 16; ++j) Wqk[(long)vh * 4096 + d * 64 + e0 + j] = acc[j];
}

// ---------------------------------------------------------------------------
// K0c: tB[b][v][h][e] = 0.125 * sum_d ha[b][v][h*64+d] * Wqk[v][h][d][e]
// ---------------------------------------------------------------------------
__global__ __launch_bounds__(256) void k_tq(
    const float* __restrict__ ha, const float* __restrict__ Wqk,
    float* __restrict__ tB)
{
  __shared__ float hs[512];
  int bv = blockIdx.x, t = threadIdx.x;
  int v = bv % 3;
  hs[t]       = ha[(long)bv * 512 + t];
  hs[256 + t] = ha[(long)bv * 512 + 256 + t];
  __syncthreads();
  int h = t >> 5, e0 = (t & 31) * 2;
  const float* wq = Wqk + ((long)v * 8 + h) * 4096 + e0;
  const float* hv = &hs[h * 64];
  float a0 = 0.f, a1 = 0.f;
  #pragma unroll 4
  for (int d = 0; d < 64; ++d) {
    float x = hv[d];
    float2 wv = *(const float2*)&wq[d * 64];
    a0 += x * wv.x;
    a1 += x * wv.y;
  }
  tB[(long)bv * 512 + h * 64 + e0]     = a0 * 0.125f;
  tB[(long)bv * 512 + h * 64 + e0 + 1] = a1 * 0.125f;
}

// ---------------------------------------------------------------------------
// K1 (anchor only): [64 x 512] = [64 x 256] @ [256 x 512] bf16 MFMA GEMM
// + bias + LN.  mode 1: block = 64 b's for one v; out ha fp32 [b][v][512].
// ---------------------------------------------------------------------------
union K1Smem {
  struct { u16 A[64 * 256]; u16 B[16384]; } p;   // 32 KB + 32 KB
  u16 S[64 * 512];                               // 64 KB (epilogue)
};

__global__ __launch_bounds__(512, 4) void k1_gemm_ln(
    const float* __restrict__ X,
    const u16*   __restrict__ Wt,
    const float* __restrict__ bias,
    const float* __restrict__ gamma,
    const float* __restrict__ betap,
    u16*   __restrict__ hn,
    float* __restrict__ ha,
    int mode, int b0, int Bc)
{
  __shared__ K1Smem sm;
  const int v = blockIdx.y, blk = blockIdx.x, t = threadIdx.x;
  const int w = t >> 6, l = t & 63, lm = l & 15, lg = l >> 4;
  const int wm = w & 1, wn = w >> 1;

  float bcol[8];
  #pragma unroll
  for (int tn = 0; tn < 8; ++tn) bcol[tn] = bias[v * 512 + wn * 128 + tn * 16 + lm];

  {
    int row = t >> 3;
    int cbase = (t & 7) * 32;
    long grow;
    if (mode == 0) { int b = b0 + blk * 2 + (row >> 5); grow = ((long)(b * 3 + v) * 32 + (row & 31)) * 256; }
    else           { int b = blk * 64 + row;            grow = (long)(b * 3 + v) * 256; }
    const float4* src = (const float4*)(X + grow + cbase);
    int sw = row & 7;
    #pragma unroll
    for (int j = 0; j < 8; ++j) {
      float4 f = src[j];
      int col = cbase + j * 4;
      int c = col >> 3, m = col & 7;
      ushort4 u;
      u.x = f2bf(f.x); u.y = f2bf(f.y); u.z = f2bf(f.z); u.w = f2bf(f.w);
      *(ushort4*)&sm.p.A[row * 256 + ((c ^ sw) << 3) + m] = u;
    }
  }

  f4 acc[2][8];
  #pragma unroll
  for (int i = 0; i < 2; ++i)
    #pragma unroll
    for (int j = 0; j < 8; ++j) { f4 z = {0.f, 0.f, 0.f, 0.f}; acc[i][j] = z; }

  const u16* Wbase = Wt + (long)v * 8 * 16384;
  for (int kt = 0; kt < 8; ++kt) {
    __syncthreads();
    {
      const u16* gp = Wbase + (long)kt * 16384 + t * 8;
      u16* lp = &sm.p.B[t * 8];
      #pragma unroll
      for (int r = 0; r < 4; ++r) gl2lds16(gp + r * 4096, lp + r * 4096);
    }
    __syncthreads();
    bf8 af[2];
    #pragma unroll
    for (int tm = 0; tm < 2; ++tm) {
      int row = wm * 32 + tm * 16 + lm;
      int c = kt * 4 + lg;
      af[tm] = *(const bf8*)&sm.p.A[row * 256 + ((c ^ (row & 7)) << 3)];
    }
    #pragma unroll
    for (int tn = 0; tn < 8; ++tn) {
      int n = wn * 128 + tn * 16 + lm;
      bf8 bv = *(const bf8*)&sm.p.B[n * 32 + ((lg ^ ((n >> 1) & 3)) << 3)];
      acc[0][tn] = __builtin_amdgcn_mfma_f32_16x16x32_bf16(af[0], bv, acc[0][tn], 0, 0, 0);
      acc[1][tn] = __builtin_amdgcn_mfma_f32_16x16x32_bf16(af[1], bv, acc[1][tn], 0, 0, 0);
    }
  }
  __syncthreads();

  #pragma unroll
  for (int tm = 0; tm < 2; ++tm)
    #pragma unroll
    for (int tn = 0; tn < 8; ++tn) {
      int col = wn * 128 + tn * 16 + lm;
      int c = col >> 3, m = col & 7;
      #pragma unroll
      for (int r = 0; r < 4; ++r) {
        int row = wm * 32 + tm * 16 + lg * 4 + r;
        sm.S[row * 512 + ((c ^ (row & 7)) << 3) + m] = f2bf(acc[tm][tn][r] + bcol[tn]);
      }
    }
  __syncthreads();

  {
    int row = t >> 3, ch = t & 7, sw = row & 7;
    float s1 = 0.f, s2 = 0.f;
    #pragma unroll
    for (int j = 0; j < 8; ++j) {
      int c = j * 8 + ch;
      uint4 q = *(const uint4*)&sm.S[row * 512 + ((c ^ sw) << 3)];
      float x0 = bflo(q.x), x1 = bfhi(q.x), x2 = bflo(q.y), x3 = bfhi(q.y);
      float x4 = bflo(q.z), x5 = bfhi(q.z), x6 = bflo(q.w), x7 = bfhi(q.w);
      s1 += ((x0 + x1) + (x2 + x3)) + ((x4 + x5) + (x6 + x7));
      s2 += ((x0*x0 + x1*x1) + (x2*x2 + x3*x3)) + ((x4*x4 + x5*x5) + (x6*x6 + x7*x7));
    }
    #pragma unroll
    for (int d = 1; d < 8; d <<= 1) { s1 += __shfl_xor(s1, d, 64); s2 += __shfl_xor(s2, d, 64); }
    float mu = s1 * (1.f / 512.f);
    float var = s2 * (1.f / 512.f) - mu * mu;
    float rs = rsqrtf(var + 1e-5f);
    #pragma unroll
    for (int j = 0; j < 8; ++j) {
      int c = j * 8 + ch;
      uint4 q = *(const uint4*)&sm.S[row * 512 + ((c ^ sw) << 3)];
      int col0 = c * 8;
      float4 g0 = *(const float4*)&gamma[v * 512 + col0];
      float4 g1 = *(const float4*)&gamma[v * 512 + col0 + 4];
      float4 e0 = *(const float4*)&betap[v * 512 + col0];
      float4 e1 = *(const float4*)&betap[v * 512 + col0 + 4];
      float y0 = (bflo(q.x) - mu) * rs * g0.x + e0.x;
      float y1 = (bfhi(q.x) - mu) * rs * g0.y + e0.y;
      float y2 = (bflo(q.y) - mu) * rs * g0.z + e0.z;
      float y3 = (bfhi(q.y) - mu) * rs * g0.w + e0.w;
      float y4 = (bflo(q.z) - mu) * rs * g1.x + e1.x;
      float y5 = (bfhi(q.z) - mu) * rs * g1.y + e1.y;
      float y6 = (bflo(q.w) - mu) * rs * g1.z + e1.z;
      float y7 = (bfhi(q.w) - mu) * rs * g1.w + e1.w;
      if (mode == 0) {
        uint4 q4;
        q4.x = (u32)f2bf(y0) | ((u32)f2bf(y1) << 16);
        q4.y = (u32)f2bf(y2) | ((u32)f2bf(y3) << 16);
        q4.z = (u32)f2bf(y4) | ((u32)f2bf(y5) << 16);
        q4.w = (u32)f2bf(y6) | ((u32)f2bf(y7) << 16);
        int bl_ = blk * 2 + (row >> 5), krow = row & 31;
        u16* dst = hn + (((long)(v * 8 + j) * Bc + bl_) * 32 + krow) * 64 + ch * 8;
        *(uint4*)dst = q4;
      } else {
        int b = blk * 64 + row;
        float* dst = ha + (long)(b * 3 + v) * 512 + col0;
        float4 w0, w1;
        w0.x = y0; w0.y = y1; w0.z = y2; w0.w = y3;
        w1.x = y4; w1.y = y5; w1.z = y6; w1.w = y7;
        *(float4*)dst = w0;
        *(float4*)(dst + 4) = w1;
      }
    }
  }
}

// ---------------------------------------------------------------------------
// K12 v3: FUSED neighbor encoder + per-view attention.
//  - Swapped-operand MFMA: acc = mfma(bv, af, acc) -> lane holds 2 rows x
//    32 CONSECUTIVE cols (cols = wn*128+tn*16+lg*4+r). Numerically identical.
//  - bias folded into acc (no bcol live across GEMM loop -> no spill)
//  - LayerNorm stats from fp32 accumulators (in-reg sums + 2 shfl + 2.5KB
//    LDS partial reduce); S written ONCE, normalized, via ds_write_b64.
//  - haS dropped (ha re-read coalesced in final phase); LN partials alias oS.
// ---------------------------------------------------------------------------
__global__ __launch_bounds__(512, 4) void k12_fused(
    const float* __restrict__ X,      // x_neighbors
    const u16*   __restrict__ Wt,     // nWt (swizzled LDS-image tiles)
    const float* __restrict__ bias,   // nb
    const float* __restrict__ gamma,  // ng
    const float* __restrict__ betap,  // nbeta
    const float* __restrict__ ha,     // [B][V][512] f32
    const u16*   __restrict__ Wvt,    // [V][H][64][64] bf16 transposed
    const float* __restrict__ tB,     // [B][V][H][64] f32 = ha@Wqk * 0.125
    const float* __restrict__ Wo,     // [V][H][64][64] f32
    const float* __restrict__ ew,     // [B][V][K]
    const float* __restrict__ gls,    // [V][H]
    float* __restrict__ vt)           // [B][H][V][64]
{
  __shared__ K1Smem sm;
  __shared__ float tS[1024];      // [2b][8h][64e]
  __shared__ float aS[512];       // [2b][8h][32k]
  __shared__ float oSbuf[1024];   // V-proj o's; earlier: LN partials
  float* lnP1 = oSbuf;            // [64 rows][4 wn]
  float* lnP2 = oSbuf + 256;      // [64 rows][4 wn]
  float* muRs = oSbuf + 512;      // [0..63]=mu, [64..127]=rs

  const int v = blockIdx.y, blk = blockIdx.x, t = threadIdx.x;
  const int w = t >> 6, l = t & 63, lm = l & 15, lg = l >> 4;
  const int wm = w & 1, wn = w >> 1;

  // ---- stage A once (fp32 -> bf16, XOR-swizzled rows): 2 b's x 32 k ----
  {
    int row = t >> 3;
    int cbase = (t & 7) * 32;
    int b = blk * 2 + (row >> 5);
    long grow = ((long)(b * 3 + v) * 32 + (row & 31)) * 256;
    const float4* src = (const float4*)(X + grow + cbase);
    int sw = row & 7;
    #pragma unroll
    for (int j = 0; j < 8; ++j) {
      float4 f = src[j];
      int col = cbase + j * 4;
      int c = col >> 3, m = col & 7;
      ushort4 u;
      u.x = f2bf(f.x); u.y = f2bf(f.y); u.z = f2bf(f.z); u.w = f2bf(f.w);
      *(ushort4*)&sm.p.A[row * 256 + ((c ^ sw) << 3) + m] = u;
    }
  }
  // ---- stage precomputed tB for both b's ----
  {
    int b = t >> 8, e = (t & 255) * 2;
    *(float2*)&tS[b * 512 + e] =
        *(const float2*)&tB[((long)(blk * 2 + b) * 3 + v) * 512 + e];
  }

  f4 acc[2][8];
  #pragma unroll
  for (int i = 0; i < 2; ++i)
    #pragma unroll
    for (int j = 0; j < 8; ++j) { f4 z = {0.f, 0.f, 0.f, 0.f}; acc[i][j] = z; }

  // ---- K loop: 2 barriers/kt, B via async DMA; SWAPPED mfma operands ----
  const u16* Wbase = Wt + (long)v * 8 * 16384;
  for (int kt = 0; kt < 8; ++kt) {
    __syncthreads();
    {
      const u16* gp = Wbase + (long)kt * 16384 + t * 8;
      u16* lp = &sm.p.B[t * 8];
      #pragma unroll
      for (int r = 0; r < 4; ++r) gl2lds16(gp + r * 4096, lp + r * 4096);
    }
    __syncthreads();
    bf8 af[2];
    #pragma unroll
    for (int tm = 0; tm < 2; ++tm) {
      int row = wm * 32 + tm * 16 + lm;
      int c = kt * 4 + lg;
      af[tm] = *(const bf8*)&sm.p.A[row * 256 + ((c ^ (row & 7)) << 3)];
    }
    #pragma unroll
    for (int tn = 0; tn < 8; ++tn) {
      int n = wn * 128 + tn * 16 + lm;
      bf8 bv = *(const bf8*)&sm.p.B[n * 32 + ((lg ^ ((n >> 1) & 3)) << 3)];
      // swapped: D = (X W)^T tile -> lane lm = X-row, regs = 4 consecutive n
      acc[0][tn] = __builtin_amdgcn_mfma_f32_16x16x32_bf16(bv, af[0], acc[0][tn], 0, 0, 0);
      acc[1][tn] = __builtin_amdgcn_mfma_f32_16x16x32_bf16(bv, af[1], acc[1][tn], 0, 0, 0);
    }
  }

  // ---- bias into acc (transient loads; frees regs for GEMM loop) ----
  #pragma unroll
  for (int tn = 0; tn < 8; ++tn) {
    float4 bb = *(const float4*)&bias[v * 512 + wn * 128 + tn * 16 + lg * 4];
    #pragma unroll
    for (int r = 0; r < 4; ++r) { acc[0][tn][r] += ((const float*)&bb)[r]; acc[1][tn][r] += ((const float*)&bb)[r]; }
  }

  // ---- LN stats from fp32 acc: in-lane 32-col sums, shfl over lg, LDS ----
  {
    #pragma unroll
    for (int tm = 0; tm < 2; ++tm) {
      float s1 = 0.f, s2 = 0.f;
      #pragma unroll
      for (int tn = 0; tn < 8; ++tn)
        #pragma unroll
        for (int r = 0; r < 4; ++r) { float z = acc[tm][tn][r]; s1 += z; s2 += z * z; }
      s1 += __shfl_xor(s1, 16, 64); s2 += __shfl_xor(s2, 16, 64);
      s1 += __shfl_xor(s1, 32, 64); s2 += __shfl_xor(s2, 32, 64);
      if (lg == 0) {
        int row = wm * 32 + tm * 16 + lm;
        lnP1[row * 4 + wn] = s1;
        lnP2[row * 4 + wn] = s2;
      }
    }
  }
  __syncthreads();
  if (t < 64) {
    float p = lnP1[t * 4] + lnP1[t * 4 + 1] + lnP1[t * 4 + 2] + lnP1[t * 4 + 3];
    float q = lnP2[t * 4] + lnP2[t * 4 + 1] + lnP2[t * 4 + 2] + lnP2[t * 4 + 3];
    float mu = p * (1.f / 512.f);
    float var = q * (1.f / 512.f) - mu * mu;
    muRs[t]      = mu;
    muRs[64 + t] = rsqrtf(var + 1e-5f);
  }
  __syncthreads();

  // ---- normalize from acc, pack bf16 x4, single b64 write into S ----
  {
    float mu0 = muRs[wm * 32 + lm],      rs0 = muRs[64 + wm * 32 + lm];
    float mu1 = muRs[wm * 32 + 16 + lm], rs1 = muRs[64 + wm * 32 + 16 + lm];
    int row0 = wm * 32 + lm, row1 = row0 + 16;
    int sw0 = row0 & 7, sw1 = row1 & 7;
    #pragma unroll
    for (int tn = 0; tn < 8; ++tn) {
      int col0 = wn * 128 + tn * 16 + lg * 4;
      int c = col0 >> 3, m0 = col0 & 7;      // m0 in {0,4}
      float4 g4 = *(const float4*)&gamma[v * 512 + col0];
      float4 b4 = *(const float4*)&betap[v * 512 + col0];
      {
        float y0 = (acc[0][tn][0] - mu0) * rs0 * g4.x + b4.x;
        float y1 = (acc[0][tn][1] - mu0) * rs0 * g4.y + b4.y;
        float y2 = (acc[0][tn][2] - mu0) * rs0 * g4.z + b4.z;
        float y3 = (acc[0][tn][3] - mu0) * rs0 * g4.w + b4.w;
        uint2 p;
        p.x = (u32)f2bf(y0) | ((u32)f2bf(y1) << 16);
        p.y = (u32)f2bf(y2) | ((u32)f2bf(y3) << 16);
        *(uint2*)&sm.S[row0 * 512 + ((c ^ sw0) << 3) + m0] = p;
      }
      {
        float y0 = (acc[1][tn][0] - mu1) * rs1 * g4.x + b4.x;
        float y1 = (acc[1][tn][1] - mu1) * rs1 * g4.y + b4.y;
        float y2 = (acc[1][tn][2] - mu1) * rs1 * g4.z + b4.z;
        float y3 = (acc[1][tn][3] - mu1) * rs1 * g4.w + b4.w;
        uint2 p;
        p.x = (u32)f2bf(y0) | ((u32)f2bf(y1) << 16);
        p.y = (u32)f2bf(y2) | ((u32)f2bf(y3) << 16);
        *(uint2*)&sm.S[row1 * 512 + ((c ^ sw1) << 3) + m0] = p;
      }
    }
  }
  __syncthreads();

  // ---- scores + softmax: thread = (b,h,k), 2*8*32 = 512 ----
  {
    int b = t >> 8, h = (t >> 5) & 7, k = t & 31;
    float x = gls[v * 8 + h];
    float gsc = (x > 20.f) ? x : log1pf(expf(x));
    int r = b * 32 + k, sw = r & 7;
    const float* tb = &tS[(b * 8 + h) * 64];
    float s = 0.f;
    #pragma unroll
    for (int j = 0; j < 8; ++j) {
      int c8 = h * 8 + j;
      uint4 q = *(const uint4*)&sm.S[r * 512 + ((c8 ^ sw) << 3)];
      const float* tj = tb + j * 8;
      s += tj[0] * bflo(q.x) + tj[1] * bfhi(q.x)
         + tj[2] * bflo(q.y) + tj[3] * bfhi(q.y)
         + tj[4] * bflo(q.z) + tj[5] * bfhi(q.z)
         + tj[6] * bflo(q.w) + tj[7] * bfhi(q.w);
    }
    float e_w = ew[((long)(blk * 2 + b) * 3 + v) * 32 + k];
    s += gsc * logf(e_w + 1e-6f);
    float m = s;
    #pragma unroll
    for (int d = 1; d < 32; d <<= 1) m = fmaxf(m, __shfl_xor(m, d, 64));
    float exs = expf(s - m), sum = exs;
    #pragma unroll
    for (int d = 1; d < 32; d <<= 1) sum += __shfl_xor(sum, d, 64);
    aS[(b * 8 + h) * 32 + k] = exs / sum;
  }
  __syncthreads();

  // ---- per wave: 2 (b,h) pairs: V-proj MFMA from S + o = attn@V ----
  #pragma unroll 1
  for (int i = 0; i < 2; ++i) {
    int p = w * 2 + i, b = p >> 3, h = p & 7;
    const u16* wvg = Wvt + (long)(v * 8 + h) * 4096;
    f4 aV[2][4];
    #pragma unroll
    for (int a = 0; a < 2; ++a)
      #pragma unroll
      for (int j = 0; j < 4; ++j) { f4 z = {0.f, 0.f, 0.f, 0.f}; aV[a][j] = z; }
    #pragma unroll
    for (int ks = 0; ks < 2; ++ks) {
      int ko = ks * 32 + lg * 8;
      bf8 af[2];
      #pragma unroll
      for (int tm = 0; tm < 2; ++tm) {
        int r = b * 32 + tm * 16 + lm;
        int c8 = h * 8 + ks * 4 + lg;
        af[tm] = *(const bf8*)&sm.S[r * 512 + ((c8 ^ (r & 7)) << 3)];
      }
      #pragma unroll
      for (int tn = 0; tn < 4; ++tn) {
        bf8 bv = *(const bf8*)&wvg[(tn * 16 + lm) * 64 + ko];
        #pragma unroll
        for (int tm = 0; tm < 2; ++tm)
          aV[tm][tn] = __builtin_amdgcn_mfma_f32_16x16x32_bf16(af[tm], bv, aV[tm][tn], 0, 0, 0);
      }
    }
    float pp[4] = {0.f, 0.f, 0.f, 0.f};
    #pragma unroll
    for (int tm = 0; tm < 2; ++tm)
      #pragma unroll
      for (int r4 = 0; r4 < 4; ++r4) {
        int k = tm * 16 + lg * 4 + r4;
        float a = aS[p * 32 + k];
        #pragma unroll
        for (int tn = 0; tn < 4; ++tn) pp[tn] += a * aV[tm][tn][r4];
      }
    #pragma unroll
    for (int tn = 0; tn < 4; ++tn) {
      float x = pp[tn];
      x += __shfl_xor(x, 16, 64);
      x += __shfl_xor(x, 32, 64);
      if (l < 16) oSbuf[p * 64 + tn * 16 + lm] = x;
    }
  }
  __syncthreads();

  // ---- out = o @ Wo + ha (residual, re-read); thread = (h,e) ----
  {
    int h = t >> 6, e = t & 63;
    const float* wo = Wo + (long)(v * 8 + h) * 4096;
    float a0 = ha[((long)(blk * 2 + 0) * 3 + v) * 512 + h * 64 + e];
    float a1 = ha[((long)(blk * 2 + 1) * 3 + v) * 512 + h * 64 + e];
    const float* o0 = &oSbuf[h * 64];
    const float* o1 = &oSbuf[512 + h * 64];
    #pragma unroll 8
    for (int d = 0; d < 64; ++d) {
      float wv = wo[d * 64 + e];
      a0 += o0[d] * wv;
      a1 += o1[d] * wv;
    }
    vt[(((long)(blk * 2 + 0) * 8 + h) * 3 + v) * 64 + e] = a0;
    vt[(((long)(blk * 2 + 1) * 8 + h) * 3 + v) * 64 + e] = a1;
  }
}

// ---------------------------------------------------------------------------
// K3: router MLP (fp32). Block = 4 b's (512 blocks -> full GPU).
// ---------------------------------------------------------------------------
__global__ __launch_bounds__(256) void k3_router(
    const float* __restrict__ g, const float* __restrict__ rW1, const float* __restrict__ rb1,
    const float* __restrict__ rW2, const float* __restrict__ rb2,
    const float* __restrict__ vW, const float* __restrict__ vb,
    const float* __restrict__ mW, const float* __restrict__ mb,
    const float* __restrict__ gW, const float* __restrict__ gb,
    float* __restrict__ pi, float* __restrict__ beta_o, float* __restrict__ gate_o)
{
  __shared__ float gs[4 * 128], h1[4 * 256], h2[4 * 256], lgt[4 * 40];
  int t = threadIdx.x, bb = blockIdx.x * 4;
  #pragma unroll
  for (int r = 0; r < 2; ++r) { int idx = r * 256 + t; gs[idx] = g[(long)bb * 128 + idx]; }
  __syncthreads();
  {
    int bl = t >> 6, e0 = (t & 63) * 4;
    float acc[4];
    #pragma unroll
    for (int j = 0; j < 4; ++j) acc[j] = rb1[e0 + j];
    for (int i = 0; i < 128; ++i) {
      float gv = gs[bl * 128 + i];
      const float* wr = rW1 + i * 256 + e0;
      #pragma unroll
      for (int j = 0; j < 4; ++j) acc[j] += gv * wr[j];
    }
    #pragma unroll
    for (int j = 0; j < 4; ++j) { float x = acc[j]; h1[bl * 256 + e0 + j] = 0.5f * x * (1.f + erff(x * 0.70710678118f)); }
  }
  __syncthreads();
  {
    int bl = t >> 6, e0 = (t & 63) * 4;
    float acc[4];
    #pragma unroll
    for (int j = 0; j < 4; ++j) acc[j] = rb2[e0 + j];
    for (int i = 0; i < 256; ++i) {
      float hv = h1[bl * 256 + i];
      const float* wr = rW2 + i * 256 + e0;
      #pragma unroll
      for (int j = 0; j < 4; ++j) acc[j] += hv * wr[j];
    }
    #pragma unroll
    for (int j = 0; j < 4; ++j) { float x = acc[j]; h2[bl * 256 + e0 + j] = 0.5f * x * (1.f + erff(x * 0.70710678118f)); }
  }
  __syncthreads();
  if (t < 160) {
    int bl = t / 40, j = t % 40;
    const float* W; float bs; int col, stride;
    if (j < 24)      { W = vW; col = j;      stride = 24; bs = vb[j]; }
    else if (j < 32) { W = mW; col = j - 24; stride = 8;  bs = mb[j - 24]; }
    else             { W = gW; col = j - 32; stride = 8;  bs = gb[j - 32]; }
    float acc = bs;
    for (int i = 0; i < 256; ++i) acc += h2[bl * 256 + i] * W[i * stride + col];
    lgt[bl * 40 + j] = acc;
  }
  __syncthreads();
  if (t < 4) {
    int b = bb + t;
    const float* L = &lgt[t * 40];
    #pragma unroll
    for (int hh = 0; hh < 8; ++hh) {
      float a0 = L[hh * 3], a1 = L[hh * 3 + 1], a2v = L[hh * 3 + 2];
      float m = fmaxf(a0, fmaxf(a1, a2v));
      float x0 = expf(a0 - m), x1 = expf(a1 - m), x2 = expf(a2v - m);
      float inv = 1.f / (x0 + x1 + x2);
      pi[b * 24 + hh * 3 + 0] = x0 * inv;
      pi[b * 24 + hh * 3 + 1] = x1 * inv;
      pi[b * 24 + hh * 3 + 2] = x2 * inv;
      beta_o[b * 8 + hh] = 1.f / (1.f + expf(-L[24 + hh]));
    }
    float m = L[32];
    #pragma unroll
    for (int hh = 1; hh < 8; ++hh) m = fmaxf(m, L[32 + hh]);
    float s = 0.f, ex[8];
    #pragma unroll
    for (int hh = 0; hh < 8; ++hh) { ex[hh] = expf(L[32 + hh] - m); s += ex[hh]; }
    float inv = 1.f / s;
    #pragma unroll
    for (int hh = 0; hh < 8; ++hh) gate_o[b * 8 + hh] = ex[hh] * inv;
  }
}

// ---------------------------------------------------------------------------
// K4: pi-mixture + cross-view attention + output. Block = 4 b's, fp32.
// ---------------------------------------------------------------------------
__global__ __launch_bounds__(256) void k4_cross(
    const float* __restrict__ vtg, const float* __restrict__ pig,
    const float* __restrict__ betag, const float* __restrict__ gateg,
    const float* __restrict__ cWq, const float* __restrict__ cWk,
    const float* __restrict__ cWv, const float* __restrict__ cWo,
    float* __restrict__ out)
{
  __shared__ float smem[12544];
  float* vts   = smem;          // 6144: [4][8][3][64]
  float* mixs  = smem + 6144;   // 2048
  float* buf1  = smem + 8192;   // 2048: qc, then y
  float* buf2  = smem + 10240;  // 2048: w,  then cr
  float* a2s   = smem + 12288;  // 96
  float* pis   = smem + 12384;  // 96
  float* betas = smem + 12480;  // 32
  float* gates = smem + 12512;  // 32

  int t = threadIdx.x, bblk = blockIdx.x * 4;
  {
    const float4* src = (const float4*)(vtg + (long)bblk * 1536);
    #pragma unroll
    for (int r = 0; r < 6; ++r) ((float4*)vts)[r * 256 + t] = src[r * 256 + t];
    if (t < 96) pis[t] = pig[bblk * 24 + t];
    if (t < 32) { betas[t] = betag[bblk * 8 + t]; gates[t] = gateg[bblk * 8 + t]; }
  }
  __syncthreads();
  int bl = t >> 6, hh = (t >> 3) & 7, e0 = (t & 7) * 8;
  const float* vbh = &vts[(bl * 8 + hh) * 192];
  {
    float p0 = pis[bl * 24 + hh * 3], p1 = pis[bl * 24 + hh * 3 + 1], p2 = pis[bl * 24 + hh * 3 + 2];
    #pragma unroll
    for (int j = 0; j < 8; ++j) {
      int e = e0 + j;
      mixs[(bl * 8 + hh) * 64 + e] = p0 * vbh[e] + p1 * vbh[64 + e] + p2 * vbh[128 + e];
    }
  }
  __syncthreads();
  {
    float acc[8] = {0.f,0.f,0.f,0.f,0.f,0.f,0.f,0.f};
    const float* M = &mixs[(bl * 8 + hh) * 64];
    for (int d = 0; d < 64; ++d) {
      float mv = M[d];
      const float* wr = &cWq[(hh * 64 + d) * 64 + e0];
      #pragma unroll
      for (int j = 0; j < 8; ++j) acc[j] += mv * wr[j];
    }
    #pragma unroll
    for (int j = 0; j < 8; ++j) buf1[(bl * 8 + hh) * 64 + e0 + j] = acc[j] * 0.125f;
  }
  __syncthreads();
  {
    const float* Q = &buf1[(bl * 8 + hh) * 64];
    #pragma unroll
    for (int d2 = 0; d2 < 8; ++d2) {
      const float* wr = &cWk[(hh * 64 + e0 + d2) * 64];
      float a = 0.f;
      for (int e = 0; e < 64; ++e) a += wr[e] * Q[e];
      buf2[(bl * 8 + hh) * 64 + e0 + d2] = a;
    }
  }
  __syncthreads();
  if (t < 32) {
    int b2 = t >> 3, h2 = t & 7;
    const float* Wd = &buf2[(b2 * 8 + h2) * 64];
    const float* vb2 = &vts[(b2 * 8 + h2) * 192];
    float s[3];
    #pragma unroll
    for (int v3 = 0; v3 < 3; ++v3) {
      float a = 0.f;
      for (int d = 0; d < 64; ++d) a += Wd[d] * vb2[v3 * 64 + d];
      s[v3] = a + logf(pis[b2 * 24 + h2 * 3 + v3] + 1e-6f);
    }
    float m = fmaxf(s[0], fmaxf(s[1], s[2]));
    float x0 = expf(s[0] - m), x1 = expf(s[1] - m), x2 = expf(s[2] - m);
    float inv = 1.f / (x0 + x1 + x2);
    a2s[(b2 * 8 + h2) * 3 + 0] = x0 * inv;
    a2s[(b2 * 8 + h2) * 3 + 1] = x1 * inv;
    a2s[(b2 * 8 + h2) * 3 + 2] = x2 * inv;
  }
  __syncthreads();
  {
    float a0 = a2s[(bl * 8 + hh) * 3], a1 = a2s[(bl * 8 + hh) * 3 + 1], a2v = a2s[(bl * 8 + hh) * 3 + 2];
    #pragma unroll
    for (int j = 0; j < 8; ++j) {
      int e = e0 + j;
      buf1[(bl * 8 + hh) * 64 + e] = a0 * vbh[e] + a1 * vbh[64 + e] + a2v * vbh[128 + e];
    }
  }
  __syncthreads();
  {
    float acc[8] = {0.f,0.f,0.f,0.f,0.f,0.f,0.f,0.f};
    const float* Y = &buf1[(bl * 8 + hh) * 64];
    for (int d = 0; d < 64; ++d) {
      float yv = Y[d];
      const float* wr = &cWv[(hh * 64 + d) * 64 + e0];
      #pragma unroll
      for (int j = 0; j < 8; ++j) acc[j] += yv * wr[j];
    }
    #pragma unroll
    for (int j = 0; j < 8; ++j) buf2[(bl * 8 + hh) * 64 + e0 + j] = acc[j];
  }
  __syncthreads();
  {
    float acc[8] = {0.f,0.f,0.f,0.f,0.f,0.f,0.f,0.f};
    const float* C2 = &buf2[(bl * 8 + hh) * 64];
    for (int d = 0; d < 64; ++d) {
      float cv = C2[d];
      const float* wr = &cWo[(hh * 64 + d) * 64 + e0];
      #pragma unroll
      for (int j = 0; j < 8; ++j) acc[j] += cv * wr[j];
    }
    float bt = betas[bl * 8 + hh], gt = gates[bl * 8 + hh];
    const float* M = &mixs[(bl * 8 + hh) * 64];
    #pragma unroll
    for (int j = 0; j < 8; ++j)
      out[((long)(bblk + bl) * 8 + hh) * 64 + e0 + j] = gt * (bt * acc[j] + (1.f - bt) * M[e0 + j]);
  }
}

// ---------------------------------------------------------------------------
extern "C" void kernel_launch(void* const* d_in, const int* in_sizes, int n_in,
                              void* d_out, int out_size, void* d_ws, size_t ws_size,
                              hipStream_t stream) {
  const float* x_anchor    = (const float*)d_in[0];
  const float* x_neighbors = (const float*)d_in[1];
  const float* edge_w      = (const float*)d_in[2];
  const float* g           = (const float*)d_in[3];
  const float* aW  = (const float*)d_in[4];
  const float* ab  = (const float*)d_in[5];
  const float* ag  = (const float*)d_in[6];
  const float* abeta = (const float*)d_in[7];
  const float* nW  = (const float*)d_in[8];
  const float* nb  = (const float*)d_in[9];
  const float* ng  = (const float*)d_in[10];
  const float* nbeta = (const float*)d_in[11];
  const float* Wq  = (const float*)d_in[12];
  const float* Wk  = (const float*)d_in[13];
  const float* Wv  = (const float*)d_in[14];
  const float* Wo  = (const float*)d_in[15];
  const float* gls = (const float*)d_in[16];
  const float* cWq = (const float*)d_in[17];
  const float* cWk = (const float*)d_in[18];
  const float* cWv = (const float*)d_in[19];
  const float* cWo = (const float*)d_in[20];
  const float* rW1 = (const float*)d_in[21];
  const float* rb1 = (const float*)d_in[22];
  const float* rW2 = (const float*)d_in[23];
  const float* rb2 = (const float*)d_in[24];
  const float* vW  = (const float*)d_in[25];
  const float* vb  = (const float*)d_in[26];
  const float* mW  = (const float*)d_in[27];
  const float* mb  = (const float*)d_in[28];
  const float* gW  = (const float*)d_in[29];
  const float* gb  = (const float*)d_in[30];

  // workspace carve-up
  char* p = (char*)d_ws;
  u16* nWt = (u16*)p;  p += 786432;
  u16* aWt = (u16*)p;  p += 786432;
  u16* Wvt = (u16*)p;  p += 196608;
  float* WqkB = (float*)p; p += 393216;
  float* ha   = (float*)p; p += 12582912;
  float* vtb  = (float*)p; p += 12582912;
  float* tqB  = (float*)p; p += 12582912;
  float* pib  = (float*)p; p += 196608;
  float* betb = (float*)p; p += 65536;
  float* gatb = (float*)p; p += 65536;
  (void)ws_size;

  k0_prep<<<1920, 256, 0, stream>>>(nW, aW, Wv, nWt, aWt, Wvt);
  k0_wqk<<<24, 256, 0, stream>>>(Wq, Wk, WqkB);
  // anchor encoder: ha (fp32)
  k1_gemm_ln<<<dim3(32, 3), 512, 0, stream>>>(x_anchor, aWt, ab, ag, abeta,
                                              (u16*)nullptr, ha, 1, 0, 2048);
  // tB = (ha @ Wqk) * 0.125, hoisted out of the fused kernel
  k_tq<<<6144, 256, 0, stream>>>(ha, WqkB, tqB);
  k3_router<<<512, 256, 0, stream>>>(g, rW1, rb1, rW2, rb2, vW, vb, mW, mb, gW, gb,
                                     pib, betb, gatb);
  // fused neighbor encoder + per-view attention (single pass over B)
  k12_fused<<<dim3(1024, 3), 512, 0, stream>>>(x_neighbors, nWt, nb, ng, nbeta,
                                               ha, Wvt, tqB, Wo, edge_w, gls, vtb);
  k4_cross<<<512, 256, 0, stream>>>(vtb, pib, betb, gatb, cWq, cWk, cWv, cWo,
                                    (float*)d_out);
}